// Round 18
// baseline (91.521 us; speedup 1.0000x reference)
//
#include <hip/hip_runtime.h>
#include <hip/hip_bf16.h>

typedef __attribute__((ext_vector_type(4))) float f32x4;
typedef __attribute__((ext_vector_type(8))) short s16x8;
typedef __attribute__((ext_vector_type(4))) short s16x4;

#define LOG2E 1.4426950408889634f

__device__ __forceinline__ ushort f2bf(float f){
  union { float f; unsigned u; } x; x.f = f;
  unsigned r = x.u + 0x7fffu + ((x.u >> 16) & 1u);
  return (ushort)(r >> 16);
}
__device__ __forceinline__ float bf2f(ushort h){
  union { unsigned u; float f; } x; x.u = ((unsigned)h) << 16;
  return x.f;
}

// fast 2^x: single v_exp_f32 (libm exp2f is NOT this without -ffast-math)
__device__ __forceinline__ float fexp2(float x){
#if __has_builtin(__builtin_amdgcn_exp2f)
  return __builtin_amdgcn_exp2f(x);
#else
  float r; asm("v_exp_f32 %0, %1" : "=v"(r) : "v"(x)); return r;
#endif
}

__device__ __forceinline__ void gload16(const void* g, void* l){
  __builtin_amdgcn_global_load_lds(
      (const __attribute__((address_space(1))) void*)g,
      (__attribute__((address_space(3))) void*)l, 16, 0, 0);
}

// K=16 bf16 MFMA (A,B = 4 bf16 in 2 VGPRs).
#if __has_builtin(__builtin_amdgcn_mfma_f32_16x16x16bf16_1k)
__device__ __forceinline__ f32x4 mfma16(s16x4 a, s16x4 b, f32x4 c){
  return __builtin_amdgcn_mfma_f32_16x16x16bf16_1k(a, b, c, 0, 0, 0);
}
#elif __has_builtin(__builtin_amdgcn_mfma_f32_16x16x16_bf16)
__device__ __forceinline__ f32x4 mfma16(s16x4 a, s16x4 b, f32x4 c){
  return __builtin_amdgcn_mfma_f32_16x16x16_bf16(a, b, c, 0, 0, 0);
}
#else
__device__ __forceinline__ f32x4 mfma16(s16x4 a, s16x4 b, f32x4 c){
  f32x4 d;
  asm volatile("v_mfma_f32_16x16x16_bf16 %0, %1, %2, %3\n\ts_nop 7\n\ts_nop 7"
               : "=v"(d) : "v"(a), "v"(b), "v"(c));
  return d;
}
#endif

// ---------------------------------------------------------------------------
// Kernel A: MFMA Q/K/V projections, self-contained weight conversion.
//  Grid 1024 = b(4) x ntile(64) x oq(4). ONE 32KB x-tile staged
//  sequentially: xr -> Q, restage xi -> K,V. 4 blocks/CU.
//  Q scaled by log2(e) (exp2-domain softmax), stored hi+lo bf16;
//  K stored hi only; V stored bf16 [o][n].
// ---------------------------------------------------------------------------
__global__ __launch_bounds__(256, 4) void proj_qkv(
    const float* __restrict__ xr, const float* __restrict__ xi,
    const float* __restrict__ wq, const float* __restrict__ wk,
    const float* __restrict__ wv,
    const float* __restrict__ bq, const float* __restrict__ bk,
    const float* __restrict__ bv,
    ushort* __restrict__ Qh, ushort* __restrict__ Ql,
    ushort* __restrict__ Kh, ushort* __restrict__ Vt)
{
  __shared__ __align__(16) float xL[128*64];      // 32 KB, reused xr then xi
  const int tid = threadIdx.x;
  const int idx = blockIdx.x;
  const int oq  = idx & 3;
  const int nt  = (idx >> 2) & 63;
  const int b   = idx >> 8;
  const int n0  = nt << 6;
  const int lane = tid & 63;
  const int w    = tid >> 6;
  const int l15  = lane & 15;
  const int g    = lane >> 4;
  const int obase = oq << 4;                      // 16 outputs per projection

  #define STAGE_X(src)                                                    \
  {                                                                       \
    const float* xs = (src) + (size_t)b*524288 + n0;                      \
    _Pragma("unroll")                                                     \
    for (int j = 0; j < 8; ++j){                                          \
      int row = j*16 + (tid >> 4);                                        \
      int ch  = tid & 15;                                                 \
      gload16(xs + (size_t)row*4096 + ch*4, xL + j*1024 + w*256);         \
    }                                                                     \
  }
  #define BUILD_FRAGS(fh, fl)                                             \
  {                                                                       \
    const int px = w*16 + l15;                                            \
    _Pragma("unroll")                                                     \
    for (int kc = 0; kc < 4; ++kc){                                       \
      _Pragma("unroll")                                                   \
      for (int j = 0; j < 8; ++j){                                        \
        int r = kc*32 + g*8 + j;                                          \
        float a = xL[r*64 + px];                                          \
        ushort h = f2bf(a);                                               \
        fh[kc][j] = (short)h;                                             \
        fl[kc][j] = (short)f2bf(a - bf2f(h));                             \
      }                                                                   \
    }                                                                     \
  }
  #define LOAD_WFRAGS(wp, wh, wl4)                                        \
  {                                                                       \
    _Pragma("unroll")                                                     \
    for (int kc = 0; kc < 4; ++kc){                                       \
      const float* src = (wp) + (obase + l15)*128 + kc*32 + g*8;          \
      f32x4 a0 = *(const f32x4*)(src);                                    \
      f32x4 a1 = *(const f32x4*)(src + 4);                                \
      _Pragma("unroll")                                                   \
      for (int e = 0; e < 4; ++e){                                        \
        ushort h0 = f2bf(a0[e]);                                          \
        wh[kc][e]   = (short)h0;                                          \
        wl4[kc][e]  = (short)f2bf(a0[e] - bf2f(h0));                      \
        ushort h1 = f2bf(a1[e]);                                          \
        wh[kc][4+e]  = (short)h1;                                         \
        wl4[kc][4+e] = (short)f2bf(a1[e] - bf2f(h1));                     \
      }                                                                   \
    }                                                                     \
  }

  // ---- phase 1: range_x -> Q ----
  STAGE_X(xr);
  __syncthreads();
  {
    s16x8 xh[4], xl4[4];
    BUILD_FRAGS(xh, xl4);
    s16x8 wfh[4], wfl[4];
    LOAD_WFRAGS(wq, wfh, wfl);
    f32x4 acc = {0.f,0.f,0.f,0.f};
    #pragma unroll
    for (int kc = 0; kc < 4; ++kc){
      acc = __builtin_amdgcn_mfma_f32_16x16x32_bf16(xh[kc],  wfh[kc], acc, 0,0,0);
      acc = __builtin_amdgcn_mfma_f32_16x16x32_bf16(xl4[kc], wfh[kc], acc, 0,0,0);
      acc = __builtin_amdgcn_mfma_f32_16x16x32_bf16(xh[kc],  wfl[kc], acc, 0,0,0);
    }
    float bqv = bq[obase + l15];
    #pragma unroll
    for (int r = 0; r < 4; ++r){
      float q = (acc[r] + bqv) * LOG2E;           // exp2-domain pre-scale
      ushort hi = f2bf(q);
      size_t a = (size_t)(b*4096 + n0 + w*16 + g*4 + r)*64 + obase + l15;
      Qh[a] = hi; Ql[a] = f2bf(q - bf2f(hi));
    }
  }
  __syncthreads();                                // all waves done reading xL

  // ---- phase 2: img -> K, V ----
  STAGE_X(xi);
  __syncthreads();
  {
    s16x8 xh[4], xl4[4];
    BUILD_FRAGS(xh, xl4);
    // K (hi output only)
    {
      s16x8 wfh[4], wfl[4];
      LOAD_WFRAGS(wk, wfh, wfl);
      f32x4 acc = {0.f,0.f,0.f,0.f};
      #pragma unroll
      for (int kc = 0; kc < 4; ++kc){
        acc = __builtin_amdgcn_mfma_f32_16x16x32_bf16(xh[kc],  wfh[kc], acc, 0,0,0);
        acc = __builtin_amdgcn_mfma_f32_16x16x32_bf16(xl4[kc], wfh[kc], acc, 0,0,0);
        acc = __builtin_amdgcn_mfma_f32_16x16x32_bf16(xh[kc],  wfl[kc], acc, 0,0,0);
      }
      float bkv = bk[obase + l15];
      #pragma unroll
      for (int r = 0; r < 4; ++r){
        size_t a = (size_t)(b*4096 + n0 + w*16 + g*4 + r)*64 + obase + l15;
        Kh[a] = f2bf(acc[r] + bkv);
      }
    }
    // V (swapped operands -> [o][n] layout)
    {
      s16x8 wfh[4], wfl[4];
      LOAD_WFRAGS(wv, wfh, wfl);
      f32x4 acc = {0.f,0.f,0.f,0.f};
      #pragma unroll
      for (int kc = 0; kc < 4; ++kc){
        acc = __builtin_amdgcn_mfma_f32_16x16x32_bf16(wfh[kc], xh[kc],  acc, 0,0,0);
        acc = __builtin_amdgcn_mfma_f32_16x16x32_bf16(wfl[kc], xh[kc],  acc, 0,0,0);
        acc = __builtin_amdgcn_mfma_f32_16x16x32_bf16(wfh[kc], xl4[kc], acc, 0,0,0);
      }
      #pragma unroll
      for (int r = 0; r < 4; ++r){
        int o = obase + g*4 + r;
        float v = acc[r] + bv[o];
        Vt[(size_t)(b*64 + o)*4096 + n0 + w*16 + l15] = f2bf(v);
      }
    }
  }
  #undef STAGE_X
  #undef BUILD_FRAGS
  #undef LOAD_WFRAGS
}

// ---------------------------------------------------------------------------
// Kernel B: flash attention — 3-DEEP PIPELINE (T3+T4): K,V triple-buffered;
//  per iter: s_waitcnt vmcnt(4) (tile t landed, tile t+1's loads stay in
//  flight ACROSS the barrier) -> raw s_barrier -> stage(t+2) -> compute(t).
//  Removes the per-iter vmcnt(0) drain (m233's ~70% 2-phase overhead).
//  XCD-aware remap; exp2 softmax; defer-max THR=8; K,V XOR-swizzled 16B.
//  LDS: Kh 3x8K + V 3x8K = 48KB -> 4 blocks/CU. Grid 1024.
// ---------------------------------------------------------------------------
__global__ __launch_bounds__(256, 4) void flash_attn(
    const ushort* __restrict__ Qh, const ushort* __restrict__ Ql,
    const ushort* __restrict__ Kh, const ushort* __restrict__ Vt,
    float* __restrict__ Opart, float* __restrict__ Mst,
    float* __restrict__ Lst)
{
  __shared__ __align__(16) ushort khL[3][4096];   // 24KB
  __shared__ __align__(16) ushort vL[3][4096];    // 24KB (epilogue scratch too)

  const int tid  = threadIdx.x;
  const int idx  = blockIdx.x;
  // XCD-aware decode: xcd (=idx&7) fixes (b, ks-high); rest = (qt, ks-low)
  const int xcd  = idx & 7;
  const int rest = idx >> 3;                 // 0..127
  const int b    = xcd >> 1;
  const int ks   = ((xcd & 1) << 1) | (rest >> 6);
  const int qt   = rest & 63;
  const int lane = tid & 63;
  const int w    = tid >> 6;
  const int l15  = lane & 15;
  const int g    = lane >> 4;
  const int qrow = qt*64 + w*16;
  const int kv0  = ks << 10;                 // 1024 kv per split
  const int srow = lane >> 2;
  const int sg   = lane & 3;
  const int sgs  = sg ^ ((srow >> 1) & 3);   // source chunk pre-swizzle (K & V)

  const size_t qoff = ((size_t)(b*4096 + qrow + l15))*64 + g*8;
  s16x8 qh0 = *(const s16x8*)(Qh + qoff);
  s16x8 qh1 = *(const s16x8*)(Qh + qoff + 32);
  s16x8 ql0 = *(const s16x8*)(Ql + qoff);
  s16x8 ql1 = *(const s16x8*)(Ql + qoff + 32);

  const char* KhB = (const char*)(Kh + (size_t)b*4096*64);
  const char* VB  = (const char*)(Vt + (size_t)b*64*4096);

  f32x4 o_acc[4];
  #pragma unroll
  for (int ot=0;ot<4;++ot) o_acc[ot] = (f32x4){0.f,0.f,0.f,0.f};
  float m_run = -1e30f, l_run = 0.f;

  #define STAGE_KV(kvb, bi)                                               \
  {                                                                       \
    size_t kr = (size_t)((kvb) + w*16 + srow)*128 + sgs*16;               \
    char* kd = (char*)khL[bi] + w*2048;                                   \
    gload16(KhB + kr,      kd);                                           \
    gload16(KhB + kr + 64, kd + 1024);                                    \
    size_t vr = (size_t)(w*16 + srow)*8192 + (size_t)(kvb)*2 + sgs*16;    \
    char* vd = (char*)vL[bi] + w*2048;                                    \
    gload16(VB + vr,      vd);                                            \
    gload16(VB + vr + 64, vd + 1024);                                     \
  }

  const int swz = (l15 >> 1) & 3;                 // row-swizzle for reads
  const int kfrag = l15*64 + (g ^ swz)*16;        // K b128 read offset

  // compute body for tile t in buffer bi
  #define COMPUTE(bi)                                                     \
  {                                                                       \
    f32x4 s[4];                                                           \
    _Pragma("unroll")                                                     \
    for (int ct=0; ct<4; ++ct){                                           \
      const char* kb = (const char*)khL[bi] + ct*2048;                    \
      s16x8 kh0 = *(const s16x8*)(kb + kfrag);                            \
      s16x8 kh1 = *(const s16x8*)(kb + 1024 + kfrag);                     \
      f32x4 acc = {0.f,0.f,0.f,0.f};                                      \
      acc = __builtin_amdgcn_mfma_f32_16x16x32_bf16(kh0, ql0, acc,0,0,0); \
      acc = __builtin_amdgcn_mfma_f32_16x16x32_bf16(kh1, ql1, acc,0,0,0); \
      acc = __builtin_amdgcn_mfma_f32_16x16x32_bf16(kh0, qh0, acc,0,0,0); \
      acc = __builtin_amdgcn_mfma_f32_16x16x32_bf16(kh1, qh1, acc,0,0,0); \
      s[ct] = acc;                                                        \
    }                                                                     \
    float mx = s[0][0];                                                   \
    _Pragma("unroll")                                                     \
    for (int ct=0;ct<4;++ct){                                             \
      _Pragma("unroll")                                                   \
      for (int r=0;r<4;++r) mx = fmaxf(mx, s[ct][r]);                     \
    }                                                                     \
    mx = fmaxf(mx, __shfl_xor(mx, 16));                                   \
    mx = fmaxf(mx, __shfl_xor(mx, 32));                                   \
    if (!__all(mx <= m_run + 8.0f)){                                      \
      float mn = fmaxf(m_run, mx);                                        \
      float sc = fexp2(m_run - mn);                                       \
      m_run = mn;                                                         \
      l_run *= sc;                                                        \
      _Pragma("unroll")                                                   \
      for (int ot=0;ot<4;++ot) o_acc[ot] *= sc;                           \
    }                                                                     \
    float rs = 0.f;                                                       \
    s16x4 pbf[4];                                                         \
    _Pragma("unroll")                                                     \
    for (int ct=0;ct<4;++ct){                                             \
      _Pragma("unroll")                                                   \
      for (int r=0;r<4;++r){                                              \
        float p = fexp2(s[ct][r] - m_run);                                \
        rs += p;                                                          \
        pbf[ct][r] = (short)f2bf(p);                                      \
      }                                                                   \
    }                                                                     \
    rs += __shfl_xor(rs, 16);                                             \
    rs += __shfl_xor(rs, 32);                                             \
    l_run += rs;                                                          \
    _Pragma("unroll")                                                     \
    for (int ot=0; ot<4; ++ot){                                           \
      const char* vbase = (const char*)vL[bi] + ot*2048 + l15*64;         \
      _Pragma("unroll")                                                   \
      for (int ct=0; ct<4; ++ct){                                         \
        int chunk = (((ct & 1) << 1) + (g >> 1)) ^ swz;                   \
        s16x4 av = *(const s16x4*)(vbase + (ct>>1)*1024 + chunk*16        \
                                   + (g&1)*8);                            \
        o_acc[ot] = mfma16(av, pbf[ct], o_acc[ot]);                       \
      }                                                                   \
    }                                                                     \
  }

  // prologue: tiles 0 and 1 in flight (8 loads outstanding)
  STAGE_KV(kv0, 0);
  STAGE_KV(kv0 + 64, 1);

  for (int t = 0; t < 15; ++t){
    // tile t's 4 loads done; tile t+1's 4 remain in flight across barrier
    asm volatile("s_waitcnt vmcnt(4)" ::: "memory");
    __builtin_amdgcn_s_barrier();
    __builtin_amdgcn_sched_barrier(0);
    if (t < 14){
      STAGE_KV(kv0 + (t+2)*64, (t+2) % 3);   // overwrites buf of tile t-1
    }
    const int bi = t % 3;
    COMPUTE(bi);
  }
  // peeled last iteration: drain everything
  asm volatile("s_waitcnt vmcnt(0)" ::: "memory");
  __builtin_amdgcn_s_barrier();
  __builtin_amdgcn_sched_barrier(0);
  COMPUTE(0);                                // 15 % 3 == 0
  #undef STAGE_KV
  #undef COMPUTE

  __syncthreads();                           // all compute done before scratch
  // ---- epilogue: O^T[o][q] in regs -> swizzled LDS transpose -> O[n][o] ----
  float* ep = (float*)((char*)vL + (size_t)w*4096);   // 4KB per wave
  #pragma unroll
  for (int ot=0;ot<4;++ot){
    int dw = l15*64 + ((ot*16 + g*4) ^ ((l15 & 7) << 2));
    *(f32x4*)(ep + dw) = o_acc[ot];      // rows q=l15, swizzled o
  }
  __syncthreads();
  {
    const int q4  = lane >> 2;
    const int seg = lane & 3;
    float* Ob = Opart + ((size_t)(ks*4 + b)*4096 + qrow)*64;
    #pragma unroll
    for (int c=0;c<4;++c){
      int o0 = seg*16 + c*4;
      f32x4 vv = *(const f32x4*)(ep + q4*64 + (o0 ^ ((q4 & 7) << 2)));
      *(f32x4*)(Ob + (size_t)q4*64 + o0) = vv;   // 1KB coalesced per inst
    }
  }
  if (lane < 16){
    Mst[(size_t)(ks*4 + b)*4096 + qrow + lane] = m_run;
    Lst[(size_t)(ks*4 + b)*4096 + qrow + lane] = l_run;
  }
}

// ---------------------------------------------------------------------------
// Kernel C: merge 4 KV-split partials (exp2 domain), then y = wc*O+bc ->
//  BN -> ReLU -> +img. Grid 512 = b(4) x ntile(64) x chalf(2):
//  halves Opart re-read traffic vs cs-split x4. Wave = 16 channels.
// ---------------------------------------------------------------------------
__global__ __launch_bounds__(256) void final_proj(
    const float* __restrict__ Opart, const float* __restrict__ Mst,
    const float* __restrict__ Lst, const float* __restrict__ wc,
    const float* __restrict__ bc, const float* __restrict__ gm,
    const float* __restrict__ bt, const float* __restrict__ mu,
    const float* __restrict__ vr, const float* __restrict__ img,
    float* __restrict__ out)
{
  __shared__ float ol[64*64];
  __shared__ float scl[4][64];
  const int tid = threadIdx.x;
  const int idx = blockIdx.x;
  const int cs  = idx & 1;
  const int nt  = (idx >> 1) & 63;
  const int b   = idx >> 7;
  const int n0  = nt << 6;

  if (tid < 64){
    size_t rid = (size_t)b*4096 + n0 + tid;
    float m0 = Mst[0*16384 + rid], m1 = Mst[1*16384 + rid];
    float m2 = Mst[2*16384 + rid], m3 = Mst[3*16384 + rid];
    float mm = fmaxf(fmaxf(m0,m1), fmaxf(m2,m3));
    float s0 = fexp2(m0-mm), s1 = fexp2(m1-mm);
    float s2 = fexp2(m2-mm), s3 = fexp2(m3-mm);
    float li = s0*Lst[0*16384+rid] + s1*Lst[1*16384+rid]
             + s2*Lst[2*16384+rid] + s3*Lst[3*16384+rid];
    float inv = 1.0f / li;
    scl[0][tid] = s0*inv; scl[1][tid] = s1*inv;
    scl[2][tid] = s2*inv; scl[3][tid] = s3*inv;
  }
  __syncthreads();

  {
    const size_t base = ((size_t)b*4096 + n0)*64;
    for (int j=0;j<16;++j){
      int flat = tid + (j << 8);
      int n = flat >> 6, o = flat & 63;
      float v = Opart[0*(size_t)16384*64 + base + flat] * scl[0][n]
              + Opart[1*(size_t)16384*64 + base + flat] * scl[1][n]
              + Opart[2*(size_t)16384*64 + base + flat] * scl[2][n]
              + Opart[3*(size_t)16384*64 + base + flat] * scl[3][n];
      ol[(o << 6) + (n ^ (o & 31))] = v;
    }
  }
  __syncthreads();

  const int lane = tid & 63;
  const int w = __builtin_amdgcn_readfirstlane(tid >> 6);
  const int c0 = (cs << 6) + (w << 4);             // 16 channels per wave

  float acc[16];
  #pragma unroll
  for (int cc=0;cc<16;++cc) acc[cc] = 0.f;

  for (int o=0;o<64;++o){
    float v = ol[(o << 6) + (lane ^ (o & 31))];
    #pragma unroll
    for (int cc=0;cc<16;++cc)
      acc[cc] = fmaf(wc[(c0+cc)*64 + o], v, acc[cc]);
  }

  #pragma unroll
  for (int cc=0;cc<16;++cc){
    int c = c0 + cc;
    float inv = gm[c] * rsqrtf(vr[c] + 1e-5f);
    float sh  = bt[c] - mu[c]*inv;
    float y = (acc[cc] + bc[c]) * inv + sh;
    y = fmaxf(y, 0.f);
    size_t gi = ((size_t)(b*128 + c))*4096 + n0 + lane;
    out[gi] = img[gi] + y;
  }
}

// ---------------------------------------------------------------------------
extern "C" void kernel_launch(void* const* d_in, const int* in_sizes, int n_in,
                              void* d_out, int out_size, void* d_ws, size_t ws_size,
                              hipStream_t stream)
{
  const float* xr = (const float*)d_in[0];
  const float* xi = (const float*)d_in[1];
  const float* wq = (const float*)d_in[2];
  const float* bq = (const float*)d_in[3];
  const float* wk = (const float*)d_in[4];
  const float* bk = (const float*)d_in[5];
  const float* wv = (const float*)d_in[6];
  const float* bv = (const float*)d_in[7];
  const float* wc = (const float*)d_in[8];
  const float* bc = (const float*)d_in[9];
  const float* gm = (const float*)d_in[10];
  const float* bt = (const float*)d_in[11];
  const float* mu = (const float*)d_in[12];
  const float* vr = (const float*)d_in[13];
  float* out = (float*)d_out;

  // ws: Qh,Ql,Kh (2MB each) + Vt 2MB + Opart 16MB + M,L 0.5MB
  const size_t SZ = (size_t)4*4096*64;
  ushort* Qhw = (ushort*)d_ws;
  ushort* Qlw = Qhw + SZ;
  ushort* Khw = Qlw + SZ;
  ushort* Vtw = Khw + SZ;
  float*  Ow  = (float*)(Vtw + SZ);
  float*  Mw  = Ow + (size_t)16*4096*64;
  float*  Lw  = Mw + (size_t)16*4096;

  proj_qkv  <<<1024, 256, 0, stream>>>(xr, xi, wq, wk, wv, bq, bk, bv,
                                       Qhw, Qlw, Khw, Vtw);
  flash_attn<<<1024, 256, 0, stream>>>(Qhw, Qlw, Khw, Vtw, Ow, Mw, Lw);
  final_proj<<<512,  256, 0, stream>>>(Ow, Mw, Lw, wc, bc, gm, bt, mu, vr, xi, out);
}

// Round 19
// 83.650 us; speedup vs baseline: 1.0941x; 1.0941x over previous
//
#include <hip/hip_runtime.h>
#include <hip/hip_bf16.h>

typedef __attribute__((ext_vector_type(4))) float f32x4;
typedef __attribute__((ext_vector_type(8))) short s16x8;
typedef __attribute__((ext_vector_type(4))) short s16x4;

#define LOG2E 1.4426950408889634f

__device__ __forceinline__ ushort f2bf(float f){
  union { float f; unsigned u; } x; x.f = f;
  unsigned r = x.u + 0x7fffu + ((x.u >> 16) & 1u);
  return (ushort)(r >> 16);
}
__device__ __forceinline__ float bf2f(ushort h){
  union { unsigned u; float f; } x; x.u = ((unsigned)h) << 16;
  return x.f;
}

// fast 2^x: single v_exp_f32 (libm exp2f is NOT this without -ffast-math)
__device__ __forceinline__ float fexp2(float x){
#if __has_builtin(__builtin_amdgcn_exp2f)
  return __builtin_amdgcn_exp2f(x);
#else
  float r; asm("v_exp_f32 %0, %1" : "=v"(r) : "v"(x)); return r;
#endif
}

__device__ __forceinline__ void gload16(const void* g, void* l){
  __builtin_amdgcn_global_load_lds(
      (const __attribute__((address_space(1))) void*)g,
      (__attribute__((address_space(3))) void*)l, 16, 0, 0);
}

// K=16 bf16 MFMA (A,B = 4 bf16 in 2 VGPRs).
#if __has_builtin(__builtin_amdgcn_mfma_f32_16x16x16bf16_1k)
__device__ __forceinline__ f32x4 mfma16(s16x4 a, s16x4 b, f32x4 c){
  return __builtin_amdgcn_mfma_f32_16x16x16bf16_1k(a, b, c, 0, 0, 0);
}
#elif __has_builtin(__builtin_amdgcn_mfma_f32_16x16x16_bf16)
__device__ __forceinline__ f32x4 mfma16(s16x4 a, s16x4 b, f32x4 c){
  return __builtin_amdgcn_mfma_f32_16x16x16_bf16(a, b, c, 0, 0, 0);
}
#else
__device__ __forceinline__ f32x4 mfma16(s16x4 a, s16x4 b, f32x4 c){
  f32x4 d;
  asm volatile("v_mfma_f32_16x16x16_bf16 %0, %1, %2, %3\n\ts_nop 7\n\ts_nop 7"
               : "=v"(d) : "v"(a), "v"(b), "v"(c));
  return d;
}
#endif

// ---------------------------------------------------------------------------
// Kernel A: MFMA Q/K/V projections, self-contained weight conversion.
//  Grid 1024 = b(4) x ntile(64) x oq(4). ONE 32KB x-tile staged
//  sequentially: xr -> Q, restage xi -> K,V. 4 blocks/CU.
//  Q scaled by log2(e) (exp2-domain softmax), stored hi+lo bf16;
//  K stored hi only; V stored bf16 [o][n].
// ---------------------------------------------------------------------------
__global__ __launch_bounds__(256, 4) void proj_qkv(
    const float* __restrict__ xr, const float* __restrict__ xi,
    const float* __restrict__ wq, const float* __restrict__ wk,
    const float* __restrict__ wv,
    const float* __restrict__ bq, const float* __restrict__ bk,
    const float* __restrict__ bv,
    ushort* __restrict__ Qh, ushort* __restrict__ Ql,
    ushort* __restrict__ Kh, ushort* __restrict__ Vt)
{
  __shared__ __align__(16) float xL[128*64];      // 32 KB, reused xr then xi
  const int tid = threadIdx.x;
  const int idx = blockIdx.x;
  const int oq  = idx & 3;
  const int nt  = (idx >> 2) & 63;
  const int b   = idx >> 8;
  const int n0  = nt << 6;
  const int lane = tid & 63;
  const int w    = tid >> 6;
  const int l15  = lane & 15;
  const int g    = lane >> 4;
  const int obase = oq << 4;                      // 16 outputs per projection

  #define STAGE_X(src)                                                    \
  {                                                                       \
    const float* xs = (src) + (size_t)b*524288 + n0;                      \
    _Pragma("unroll")                                                     \
    for (int j = 0; j < 8; ++j){                                          \
      int row = j*16 + (tid >> 4);                                        \
      int ch  = tid & 15;                                                 \
      gload16(xs + (size_t)row*4096 + ch*4, xL + j*1024 + w*256);         \
    }                                                                     \
  }
  #define BUILD_FRAGS(fh, fl)                                             \
  {                                                                       \
    const int px = w*16 + l15;                                            \
    _Pragma("unroll")                                                     \
    for (int kc = 0; kc < 4; ++kc){                                       \
      _Pragma("unroll")                                                   \
      for (int j = 0; j < 8; ++j){                                        \
        int r = kc*32 + g*8 + j;                                          \
        float a = xL[r*64 + px];                                          \
        ushort h = f2bf(a);                                               \
        fh[kc][j] = (short)h;                                             \
        fl[kc][j] = (short)f2bf(a - bf2f(h));                             \
      }                                                                   \
    }                                                                     \
  }
  #define LOAD_WFRAGS(wp, wh, wl4)                                        \
  {                                                                       \
    _Pragma("unroll")                                                     \
    for (int kc = 0; kc < 4; ++kc){                                       \
      const float* src = (wp) + (obase + l15)*128 + kc*32 + g*8;          \
      f32x4 a0 = *(const f32x4*)(src);                                    \
      f32x4 a1 = *(const f32x4*)(src + 4);                                \
      _Pragma("unroll")                                                   \
      for (int e = 0; e < 4; ++e){                                        \
        ushort h0 = f2bf(a0[e]);                                          \
        wh[kc][e]   = (short)h0;                                          \
        wl4[kc][e]  = (short)f2bf(a0[e] - bf2f(h0));                      \
        ushort h1 = f2bf(a1[e]);                                          \
        wh[kc][4+e]  = (short)h1;                                         \
        wl4[kc][4+e] = (short)f2bf(a1[e] - bf2f(h1));                     \
      }                                                                   \
    }                                                                     \
  }

  // ---- phase 1: range_x -> Q ----
  STAGE_X(xr);
  __syncthreads();
  {
    s16x8 xh[4], xl4[4];
    BUILD_FRAGS(xh, xl4);
    s16x8 wfh[4], wfl[4];
    LOAD_WFRAGS(wq, wfh, wfl);
    f32x4 acc = {0.f,0.f,0.f,0.f};
    #pragma unroll
    for (int kc = 0; kc < 4; ++kc){
      acc = __builtin_amdgcn_mfma_f32_16x16x32_bf16(xh[kc],  wfh[kc], acc, 0,0,0);
      acc = __builtin_amdgcn_mfma_f32_16x16x32_bf16(xl4[kc], wfh[kc], acc, 0,0,0);
      acc = __builtin_amdgcn_mfma_f32_16x16x32_bf16(xh[kc],  wfl[kc], acc, 0,0,0);
    }
    float bqv = bq[obase + l15];
    #pragma unroll
    for (int r = 0; r < 4; ++r){
      float q = (acc[r] + bqv) * LOG2E;           // exp2-domain pre-scale
      ushort hi = f2bf(q);
      size_t a = (size_t)(b*4096 + n0 + w*16 + g*4 + r)*64 + obase + l15;
      Qh[a] = hi; Ql[a] = f2bf(q - bf2f(hi));
    }
  }
  __syncthreads();                                // all waves done reading xL

  // ---- phase 2: img -> K, V ----
  STAGE_X(xi);
  __syncthreads();
  {
    s16x8 xh[4], xl4[4];
    BUILD_FRAGS(xh, xl4);
    // K (hi output only)
    {
      s16x8 wfh[4], wfl[4];
      LOAD_WFRAGS(wk, wfh, wfl);
      f32x4 acc = {0.f,0.f,0.f,0.f};
      #pragma unroll
      for (int kc = 0; kc < 4; ++kc){
        acc = __builtin_amdgcn_mfma_f32_16x16x32_bf16(xh[kc],  wfh[kc], acc, 0,0,0);
        acc = __builtin_amdgcn_mfma_f32_16x16x32_bf16(xl4[kc], wfh[kc], acc, 0,0,0);
        acc = __builtin_amdgcn_mfma_f32_16x16x32_bf16(xh[kc],  wfl[kc], acc, 0,0,0);
      }
      float bkv = bk[obase + l15];
      #pragma unroll
      for (int r = 0; r < 4; ++r){
        size_t a = (size_t)(b*4096 + n0 + w*16 + g*4 + r)*64 + obase + l15;
        Kh[a] = f2bf(acc[r] + bkv);
      }
    }
    // V (swapped operands -> [o][n] layout)
    {
      s16x8 wfh[4], wfl[4];
      LOAD_WFRAGS(wv, wfh, wfl);
      f32x4 acc = {0.f,0.f,0.f,0.f};
      #pragma unroll
      for (int kc = 0; kc < 4; ++kc){
        acc = __builtin_amdgcn_mfma_f32_16x16x32_bf16(wfh[kc], xh[kc],  acc, 0,0,0);
        acc = __builtin_amdgcn_mfma_f32_16x16x32_bf16(wfl[kc], xh[kc],  acc, 0,0,0);
        acc = __builtin_amdgcn_mfma_f32_16x16x32_bf16(wfh[kc], xl4[kc], acc, 0,0,0);
      }
      #pragma unroll
      for (int r = 0; r < 4; ++r){
        int o = obase + g*4 + r;
        float v = acc[r] + bv[o];
        Vt[(size_t)(b*64 + o)*4096 + n0 + w*16 + l15] = f2bf(v);
      }
    }
  }
  #undef STAGE_X
  #undef BUILD_FRAGS
  #undef LOAD_WFRAGS
}

// ---------------------------------------------------------------------------
// Kernel B: flash attention — r17 structure (empirical best 47.0us):
//  transposed orientation, per-lane exp2 softmax (v_exp_f32), defer-max
//  THR=8, K,V XOR-swizzled 16B, double-buffered, ONE barrier/iter,
//  stage(t+1) issued first. XCD-aware remap (idx&7 -> (b, ks-high)) keeps
//  each XCD's K/V slice L2-resident. LDS 32KB -> 5 blocks/CU. Grid 1024.
// ---------------------------------------------------------------------------
__global__ __launch_bounds__(256, 5) void flash_attn(
    const ushort* __restrict__ Qh, const ushort* __restrict__ Ql,
    const ushort* __restrict__ Kh, const ushort* __restrict__ Vt,
    float* __restrict__ Opart, float* __restrict__ Mst,
    float* __restrict__ Lst)
{
  __shared__ __align__(16) ushort khL[2][4096];   // 16KB
  __shared__ __align__(16) ushort vL[2][4096];    // 16KB (epilogue scratch too)

  const int tid  = threadIdx.x;
  const int idx  = blockIdx.x;
  // XCD-aware decode: xcd (=idx&7) fixes (b, ks-high); rest = (qt, ks-low)
  const int xcd  = idx & 7;
  const int rest = idx >> 3;                 // 0..127
  const int b    = xcd >> 1;
  const int ks   = ((xcd & 1) << 1) | (rest >> 6);
  const int qt   = rest & 63;
  const int lane = tid & 63;
  const int w    = tid >> 6;
  const int l15  = lane & 15;
  const int g    = lane >> 4;
  const int qrow = qt*64 + w*16;
  const int kv0  = ks << 10;                 // 1024 kv per split
  const int srow = lane >> 2;
  const int sg   = lane & 3;
  const int sgs  = sg ^ ((srow >> 1) & 3);   // source chunk pre-swizzle (K & V)

  const size_t qoff = ((size_t)(b*4096 + qrow + l15))*64 + g*8;
  s16x8 qh0 = *(const s16x8*)(Qh + qoff);
  s16x8 qh1 = *(const s16x8*)(Qh + qoff + 32);
  s16x8 ql0 = *(const s16x8*)(Ql + qoff);
  s16x8 ql1 = *(const s16x8*)(Ql + qoff + 32);

  const char* KhB = (const char*)(Kh + (size_t)b*4096*64);
  const char* VB  = (const char*)(Vt + (size_t)b*64*4096);

  f32x4 o_acc[4];
  #pragma unroll
  for (int ot=0;ot<4;++ot) o_acc[ot] = (f32x4){0.f,0.f,0.f,0.f};
  float m_run = -1e30f, l_run = 0.f;

  #define STAGE_KV(kvb, bi)                                               \
  {                                                                       \
    size_t kr = (size_t)((kvb) + w*16 + srow)*128 + sgs*16;               \
    char* kd = (char*)khL[bi] + w*2048;                                   \
    gload16(KhB + kr,      kd);                                           \
    gload16(KhB + kr + 64, kd + 1024);                                    \
    size_t vr = (size_t)(w*16 + srow)*8192 + (size_t)(kvb)*2 + sgs*16;    \
    char* vd = (char*)vL[bi] + w*2048;                                    \
    gload16(VB + vr,      vd);                                            \
    gload16(VB + vr + 64, vd + 1024);                                     \
  }

  STAGE_KV(kv0, 0);
  __syncthreads();

  const int swz = (l15 >> 1) & 3;                 // row-swizzle for reads
  const int kfrag = l15*64 + (g ^ swz)*16;        // K b128 read offset

  for (int t = 0; t < 16; ++t){
    const int cb = t & 1;

    // ---- issue next-tile staging FIRST (lands under this iter's compute) --
    if (t < 15){
      STAGE_KV(kv0 + (t+1)*64, cb ^ 1);
    }

    // ---- S^T = K Q^T : S = kh*(qh+ql), K from LDS (exp2 domain) ----
    f32x4 s[4];
    #pragma unroll
    for (int ct=0; ct<4; ++ct){
      const char* kb = (const char*)khL[cb] + ct*2048;
      s16x8 kh0 = *(const s16x8*)(kb + kfrag);
      s16x8 kh1 = *(const s16x8*)(kb + 1024 + kfrag);
      f32x4 acc = {0.f,0.f,0.f,0.f};
      acc = __builtin_amdgcn_mfma_f32_16x16x32_bf16(kh0, ql0, acc, 0, 0, 0);
      acc = __builtin_amdgcn_mfma_f32_16x16x32_bf16(kh1, ql1, acc, 0, 0, 0);
      acc = __builtin_amdgcn_mfma_f32_16x16x32_bf16(kh0, qh0, acc, 0, 0, 0);
      acc = __builtin_amdgcn_mfma_f32_16x16x32_bf16(kh1, qh1, acc, 0, 0, 0);
      s[ct] = acc;   // s[ct][r] = S2[q=qrow+l15][k = kv + ct*16 + g*4 + r]
    }

    // ---- per-lane scalar online softmax (base 2, defer-max THR=8) ----
    float mx = s[0][0];
    #pragma unroll
    for (int ct=0;ct<4;++ct){
      #pragma unroll
      for (int r=0;r<4;++r) mx = fmaxf(mx, s[ct][r]);
    }
    mx = fmaxf(mx, __shfl_xor(mx, 16));
    mx = fmaxf(mx, __shfl_xor(mx, 32));
    if (!__all(mx <= m_run + 8.0f)){
      float mn = fmaxf(m_run, mx);
      float sc = fexp2(m_run - mn);
      m_run = mn;
      l_run *= sc;
      #pragma unroll
      for (int ot=0;ot<4;++ot) o_acc[ot] *= sc;
    }
    float rs = 0.f;
    s16x4 pbf[4];
    #pragma unroll
    for (int ct=0;ct<4;++ct){
      #pragma unroll
      for (int r=0;r<4;++r){
        float p = fexp2(s[ct][r] - m_run);
        rs += p;
        pbf[ct][r] = (short)f2bf(p);
      }
    }
    rs += __shfl_xor(rs, 16);
    rs += __shfl_xor(rs, 32);
    l_run += rs;

    // ---- O^T += V^T P^T : 16 x (16x16x16) MFMAs, V via swizzled LDS ----
    #pragma unroll
    for (int ot=0; ot<4; ++ot){
      const char* vbase = (const char*)vL[cb] + ot*2048 + l15*64;
      #pragma unroll
      for (int ct=0; ct<4; ++ct){
        int chunk = (((ct & 1) << 1) + (g >> 1)) ^ swz;
        s16x4 av = *(const s16x4*)(vbase + (ct>>1)*1024 + chunk*16 + (g&1)*8);
        o_acc[ot] = mfma16(av, pbf[ct], o_acc[ot]);
      }
    }

    __syncthreads();   // single barrier: drains stage(t+1), flips buffers
  }
  #undef STAGE_KV

  // ---- epilogue: O^T[o][q] in regs -> swizzled LDS transpose -> O[n][o] ----
  float* ep = (float*)((char*)vL + (size_t)w*4096);   // 4KB per wave
  #pragma unroll
  for (int ot=0;ot<4;++ot){
    int dw = l15*64 + ((ot*16 + g*4) ^ ((l15 & 7) << 2));
    *(f32x4*)(ep + dw) = o_acc[ot];      // rows q=l15, swizzled o
  }
  __syncthreads();
  {
    const int q4  = lane >> 2;
    const int seg = lane & 3;
    float* Ob = Opart + ((size_t)(ks*4 + b)*4096 + qrow)*64;
    #pragma unroll
    for (int c=0;c<4;++c){
      int o0 = seg*16 + c*4;
      f32x4 vv = *(const f32x4*)(ep + q4*64 + (o0 ^ ((q4 & 7) << 2)));
      *(f32x4*)(Ob + (size_t)q4*64 + o0) = vv;   // 1KB coalesced per inst
    }
  }
  if (lane < 16){
    Mst[(size_t)(ks*4 + b)*4096 + qrow + lane] = m_run;
    Lst[(size_t)(ks*4 + b)*4096 + qrow + lane] = l_run;
  }
}

// ---------------------------------------------------------------------------
// Kernel C: merge 4 KV-split partials (exp2 domain), then y = wc*O+bc ->
//  BN -> ReLU -> +img. Grid 512 = b(4) x ntile(64) x chalf(2):
//  halves Opart re-read traffic vs cs-split x4. Wave = 16 channels.
// ---------------------------------------------------------------------------
__global__ __launch_bounds__(256) void final_proj(
    const float* __restrict__ Opart, const float* __restrict__ Mst,
    const float* __restrict__ Lst, const float* __restrict__ wc,
    const float* __restrict__ bc, const float* __restrict__ gm,
    const float* __restrict__ bt, const float* __restrict__ mu,
    const float* __restrict__ vr, const float* __restrict__ img,
    float* __restrict__ out)
{
  __shared__ float ol[64*64];
  __shared__ float scl[4][64];
  const int tid = threadIdx.x;
  const int idx = blockIdx.x;
  const int cs  = idx & 1;
  const int nt  = (idx >> 1) & 63;
  const int b   = idx >> 7;
  const int n0  = nt << 6;

  if (tid < 64){
    size_t rid = (size_t)b*4096 + n0 + tid;
    float m0 = Mst[0*16384 + rid], m1 = Mst[1*16384 + rid];
    float m2 = Mst[2*16384 + rid], m3 = Mst[3*16384 + rid];
    float mm = fmaxf(fmaxf(m0,m1), fmaxf(m2,m3));
    float s0 = fexp2(m0-mm), s1 = fexp2(m1-mm);
    float s2 = fexp2(m2-mm), s3 = fexp2(m3-mm);
    float li = s0*Lst[0*16384+rid] + s1*Lst[1*16384+rid]
             + s2*Lst[2*16384+rid] + s3*Lst[3*16384+rid];
    float inv = 1.0f / li;
    scl[0][tid] = s0*inv; scl[1][tid] = s1*inv;
    scl[2][tid] = s2*inv; scl[3][tid] = s3*inv;
  }
  __syncthreads();

  {
    const size_t base = ((size_t)b*4096 + n0)*64;
    for (int j=0;j<16;++j){
      int flat = tid + (j << 8);
      int n = flat >> 6, o = flat & 63;
      float v = Opart[0*(size_t)16384*64 + base + flat] * scl[0][n]
              + Opart[1*(size_t)16384*64 + base + flat] * scl[1][n]
              + Opart[2*(size_t)16384*64 + base + flat] * scl[2][n]
              + Opart[3*(size_t)16384*64 + base + flat] * scl[3][n];
      ol[(o << 6) + (n ^ (o & 31))] = v;
    }
  }
  __syncthreads();

  const int lane = tid & 63;
  const int w = __builtin_amdgcn_readfirstlane(tid >> 6);
  const int c0 = (cs << 6) + (w << 4);             // 16 channels per wave

  float acc[16];
  #pragma unroll
  for (int cc=0;cc<16;++cc) acc[cc] = 0.f;

  for (int o=0;o<64;++o){
    float v = ol[(o << 6) + (lane ^ (o & 31))];
    #pragma unroll
    for (int cc=0;cc<16;++cc)
      acc[cc] = fmaf(wc[(c0+cc)*64 + o], v, acc[cc]);
  }

  #pragma unroll
  for (int cc=0;cc<16;++cc){
    int c = c0 + cc;
    float inv = gm[c] * rsqrtf(vr[c] + 1e-5f);
    float sh  = bt[c] - mu[c]*inv;
    float y = (acc[cc] + bc[c]) * inv + sh;
    y = fmaxf(y, 0.f);
    size_t gi = ((size_t)(b*128 + c))*4096 + n0 + lane;
    out[gi] = img[gi] + y;
  }
}

// ---------------------------------------------------------------------------
extern "C" void kernel_launch(void* const* d_in, const int* in_sizes, int n_in,
                              void* d_out, int out_size, void* d_ws, size_t ws_size,
                              hipStream_t stream)
{
  const float* xr = (const float*)d_in[0];
  const float* xi = (const float*)d_in[1];
  const float* wq = (const float*)d_in[2];
  const float* bq = (const float*)d_in[3];
  const float* wk = (const float*)d_in[4];
  const float* bk = (const float*)d_in[5];
  const float* wv = (const float*)d_in[6];
  const float* bv = (const float*)d_in[7];
  const float* wc = (const float*)d_in[8];
  const float* bc = (const float*)d_in[9];
  const float* gm = (const float*)d_in[10];
  const float* bt = (const float*)d_in[11];
  const float* mu = (const float*)d_in[12];
  const float* vr = (const float*)d_in[13];
  float* out = (float*)d_out;

  // ws: Qh,Ql,Kh (2MB each) + Vt 2MB + Opart 16MB + M,L 0.5MB
  const size_t SZ = (size_t)4*4096*64;
  ushort* Qhw = (ushort*)d_ws;
  ushort* Qlw = Qhw + SZ;
  ushort* Khw = Qlw + SZ;
  ushort* Vtw = Khw + SZ;
  float*  Ow  = (float*)(Vtw + SZ);
  float*  Mw  = Ow + (size_t)16*4096*64;
  float*  Lw  = Mw + (size_t)16*4096;

  proj_qkv  <<<1024, 256, 0, stream>>>(xr, xi, wq, wk, wv, bq, bk, bv,
                                       Qhw, Qlw, Khw, Vtw);
  flash_attn<<<1024, 256, 0, stream>>>(Qhw, Qlw, Khw, Vtw, Ow, Mw, Lw);
  final_proj<<<512,  256, 0, stream>>>(Ow, Mw, Lw, wc, bc, gm, bt, mu, vr, xi, out);
}

// Round 20
// 81.069 us; speedup vs baseline: 1.1289x; 1.0318x over previous
//
#include <hip/hip_runtime.h>
#include <hip/hip_bf16.h>

typedef __attribute__((ext_vector_type(4))) float f32x4;
typedef __attribute__((ext_vector_type(8))) short s16x8;
typedef __attribute__((ext_vector_type(4))) short s16x4;

#define LOG2E 1.4426950408889634f

__device__ __forceinline__ ushort f2bf(float f){
  union { float f; unsigned u; } x; x.f = f;
  unsigned r = x.u + 0x7fffu + ((x.u >> 16) & 1u);
  return (ushort)(r >> 16);
}
__device__ __forceinline__ float bf2f(ushort h){
  union { unsigned u; float f; } x; x.u = ((unsigned)h) << 16;
  return x.f;
}

// fast 2^x: single v_exp_f32 (libm exp2f is NOT this without -ffast-math)
__device__ __forceinline__ float fexp2(float x){
#if __has_builtin(__builtin_amdgcn_exp2f)
  return __builtin_amdgcn_exp2f(x);
#else
  float r; asm("v_exp_f32 %0, %1" : "=v"(r) : "v"(x)); return r;
#endif
}

__device__ __forceinline__ void gload16(const void* g, void* l){
  __builtin_amdgcn_global_load_lds(
      (const __attribute__((address_space(1))) void*)g,
      (__attribute__((address_space(3))) void*)l, 16, 0, 0);
}

// K=16 bf16 MFMA (A,B = 4 bf16 in 2 VGPRs).
#if __has_builtin(__builtin_amdgcn_mfma_f32_16x16x16bf16_1k)
__device__ __forceinline__ f32x4 mfma16(s16x4 a, s16x4 b, f32x4 c){
  return __builtin_amdgcn_mfma_f32_16x16x16bf16_1k(a, b, c, 0, 0, 0);
}
#elif __has_builtin(__builtin_amdgcn_mfma_f32_16x16x16_bf16)
__device__ __forceinline__ f32x4 mfma16(s16x4 a, s16x4 b, f32x4 c){
  return __builtin_amdgcn_mfma_f32_16x16x16_bf16(a, b, c, 0, 0, 0);
}
#else
__device__ __forceinline__ f32x4 mfma16(s16x4 a, s16x4 b, f32x4 c){
  f32x4 d;
  asm volatile("v_mfma_f32_16x16x16_bf16 %0, %1, %2, %3\n\ts_nop 7\n\ts_nop 7"
               : "=v"(d) : "v"(a), "v"(b), "v"(c));
  return d;
}
#endif

// ---------------------------------------------------------------------------
// Kernel A: MFMA Q/K/V projections, NON-REDUNDANT staging. Grid 1024 =
//  b(4) x ntile(256); each block owns a UNIQUE 16-px x-slice ([128c][16px]
//  f32 = 8KB/phase) and computes all 64 outputs (wave w = outs [16w,16w+16)).
//  Staging traffic = exactly input size (was 4x). Per-output math is
//  bit-identical to the oq-split version. Q hi+lo (exp2-prescaled),
//  K hi only, V bf16 [o][n].
// ---------------------------------------------------------------------------
__global__ __launch_bounds__(256, 4) void proj_qkv(
    const float* __restrict__ xr, const float* __restrict__ xi,
    const float* __restrict__ wq, const float* __restrict__ wk,
    const float* __restrict__ wv,
    const float* __restrict__ bq, const float* __restrict__ bk,
    const float* __restrict__ bv,
    ushort* __restrict__ Qh, ushort* __restrict__ Ql,
    ushort* __restrict__ Kh, ushort* __restrict__ Vt)
{
  __shared__ __align__(16) float xL[128*16];      // 8 KB, reused xr then xi
  const int tid = threadIdx.x;
  const int idx = blockIdx.x;
  const int nt  = idx & 255;
  const int b   = idx >> 8;
  const int n0  = nt << 4;
  const int lane = tid & 63;
  const int w    = tid >> 6;
  const int l15  = lane & 15;
  const int g    = lane >> 4;
  const int obase = w << 4;                       // wave-uniform output base

  // stage [128c][16px] f32: chunk = 4 consecutive f32 of one row
  #define STAGE_X16(src)                                                  \
  {                                                                       \
    const float* xs = (src) + (size_t)b*524288 + n0;                      \
    _Pragma("unroll")                                                     \
    for (int rdd = 0; rdd < 2; ++rdd){                                    \
      int chunk = rdd*256 + tid;             /* 0..511 */                 \
      int c = chunk >> 2, p4 = chunk & 3;                                 \
      gload16(xs + (size_t)c*4096 + p4*4, xL + rdd*1024 + w*256);         \
    }                                                                     \
  }
  #define BUILD_FRAGS16(fh, fl)                                           \
  {                                                                       \
    _Pragma("unroll")                                                     \
    for (int kc = 0; kc < 4; ++kc){                                       \
      _Pragma("unroll")                                                   \
      for (int j = 0; j < 8; ++j){                                        \
        int c = kc*32 + g*8 + j;                                          \
        float a = xL[c*16 + l15];                                         \
        ushort h = f2bf(a);                                               \
        fh[kc][j] = (short)h;                                             \
        fl[kc][j] = (short)f2bf(a - bf2f(h));                             \
      }                                                                   \
    }                                                                     \
  }
  #define LOAD_WFRAGS(wp, wh, wl4)                                        \
  {                                                                       \
    _Pragma("unroll")                                                     \
    for (int kc = 0; kc < 4; ++kc){                                       \
      const float* src = (wp) + (obase + l15)*128 + kc*32 + g*8;          \
      f32x4 a0 = *(const f32x4*)(src);                                    \
      f32x4 a1 = *(const f32x4*)(src + 4);                                \
      _Pragma("unroll")                                                   \
      for (int e = 0; e < 4; ++e){                                        \
        ushort h0 = f2bf(a0[e]);                                          \
        wh[kc][e]   = (short)h0;                                          \
        wl4[kc][e]  = (short)f2bf(a0[e] - bf2f(h0));                      \
        ushort h1 = f2bf(a1[e]);                                          \
        wh[kc][4+e]  = (short)h1;                                         \
        wl4[kc][4+e] = (short)f2bf(a1[e] - bf2f(h1));                     \
      }                                                                   \
    }                                                                     \
  }

  // ---- phase 1: range_x -> Q (this wave's 16 outputs) ----
  STAGE_X16(xr);
  __syncthreads();
  {
    s16x8 xh[4], xl4[4];
    BUILD_FRAGS16(xh, xl4);
    s16x8 wfh[4], wfl[4];
    LOAD_WFRAGS(wq, wfh, wfl);
    f32x4 acc = {0.f,0.f,0.f,0.f};
    #pragma unroll
    for (int kc = 0; kc < 4; ++kc){
      acc = __builtin_amdgcn_mfma_f32_16x16x32_bf16(xh[kc],  wfh[kc], acc, 0,0,0);
      acc = __builtin_amdgcn_mfma_f32_16x16x32_bf16(xl4[kc], wfh[kc], acc, 0,0,0);
      acc = __builtin_amdgcn_mfma_f32_16x16x32_bf16(xh[kc],  wfl[kc], acc, 0,0,0);
    }
    float bqv = bq[obase + l15];
    #pragma unroll
    for (int r = 0; r < 4; ++r){
      float q = (acc[r] + bqv) * LOG2E;           // exp2-domain pre-scale
      ushort hi = f2bf(q);
      size_t a = (size_t)(b*4096 + n0 + g*4 + r)*64 + obase + l15;
      Qh[a] = hi; Ql[a] = f2bf(q - bf2f(hi));
    }
  }
  __syncthreads();                                // all waves done reading xL

  // ---- phase 2: img -> K, V ----
  STAGE_X16(xi);
  __syncthreads();
  {
    s16x8 xh[4], xl4[4];
    BUILD_FRAGS16(xh, xl4);
    // K (hi output only)
    {
      s16x8 wfh[4], wfl[4];
      LOAD_WFRAGS(wk, wfh, wfl);
      f32x4 acc = {0.f,0.f,0.f,0.f};
      #pragma unroll
      for (int kc = 0; kc < 4; ++kc){
        acc = __builtin_amdgcn_mfma_f32_16x16x32_bf16(xh[kc],  wfh[kc], acc, 0,0,0);
        acc = __builtin_amdgcn_mfma_f32_16x16x32_bf16(xl4[kc], wfh[kc], acc, 0,0,0);
        acc = __builtin_amdgcn_mfma_f32_16x16x32_bf16(xh[kc],  wfl[kc], acc, 0,0,0);
      }
      float bkv = bk[obase + l15];
      #pragma unroll
      for (int r = 0; r < 4; ++r){
        size_t a = (size_t)(b*4096 + n0 + g*4 + r)*64 + obase + l15;
        Kh[a] = f2bf(acc[r] + bkv);
      }
    }
    // V (swapped operands -> [o][n] layout)
    {
      s16x8 wfh[4], wfl[4];
      LOAD_WFRAGS(wv, wfh, wfl);
      f32x4 acc = {0.f,0.f,0.f,0.f};
      #pragma unroll
      for (int kc = 0; kc < 4; ++kc){
        acc = __builtin_amdgcn_mfma_f32_16x16x32_bf16(wfh[kc], xh[kc],  acc, 0,0,0);
        acc = __builtin_amdgcn_mfma_f32_16x16x32_bf16(wfl[kc], xh[kc],  acc, 0,0,0);
        acc = __builtin_amdgcn_mfma_f32_16x16x32_bf16(wfh[kc], xl4[kc], acc, 0,0,0);
      }
      #pragma unroll
      for (int r = 0; r < 4; ++r){
        int o = obase + g*4 + r;
        float v = acc[r] + bv[o];
        Vt[(size_t)(b*64 + o)*4096 + n0 + l15] = f2bf(v);
      }
    }
  }
  #undef STAGE_X16
  #undef BUILD_FRAGS16
  #undef LOAD_WFRAGS
}

// ---------------------------------------------------------------------------
// Kernel B: flash attention — r17/r19 structure (frozen, empirical best):
//  transposed orientation, per-lane exp2 softmax (v_exp_f32), defer-max
//  THR=8, K,V XOR-swizzled 16B, double-buffered, ONE barrier/iter,
//  stage(t+1) issued first. XCD-aware remap keeps K/V L2-resident.
//  LDS 32KB -> 5 blocks/CU. Grid 1024.
// ---------------------------------------------------------------------------
__global__ __launch_bounds__(256, 5) void flash_attn(
    const ushort* __restrict__ Qh, const ushort* __restrict__ Ql,
    const ushort* __restrict__ Kh, const ushort* __restrict__ Vt,
    float* __restrict__ Opart, float* __restrict__ Mst,
    float* __restrict__ Lst)
{
  __shared__ __align__(16) ushort khL[2][4096];   // 16KB
  __shared__ __align__(16) ushort vL[2][4096];    // 16KB (epilogue scratch too)

  const int tid  = threadIdx.x;
  const int idx  = blockIdx.x;
  const int xcd  = idx & 7;
  const int rest = idx >> 3;                 // 0..127
  const int b    = xcd >> 1;
  const int ks   = ((xcd & 1) << 1) | (rest >> 6);
  const int qt   = rest & 63;
  const int lane = tid & 63;
  const int w    = tid >> 6;
  const int l15  = lane & 15;
  const int g    = lane >> 4;
  const int qrow = qt*64 + w*16;
  const int kv0  = ks << 10;                 // 1024 kv per split
  const int srow = lane >> 2;
  const int sg   = lane & 3;
  const int sgs  = sg ^ ((srow >> 1) & 3);   // source chunk pre-swizzle (K & V)

  const size_t qoff = ((size_t)(b*4096 + qrow + l15))*64 + g*8;
  s16x8 qh0 = *(const s16x8*)(Qh + qoff);
  s16x8 qh1 = *(const s16x8*)(Qh + qoff + 32);
  s16x8 ql0 = *(const s16x8*)(Ql + qoff);
  s16x8 ql1 = *(const s16x8*)(Ql + qoff + 32);

  const char* KhB = (const char*)(Kh + (size_t)b*4096*64);
  const char* VB  = (const char*)(Vt + (size_t)b*64*4096);

  f32x4 o_acc[4];
  #pragma unroll
  for (int ot=0;ot<4;++ot) o_acc[ot] = (f32x4){0.f,0.f,0.f,0.f};
  float m_run = -1e30f, l_run = 0.f;

  #define STAGE_KV(kvb, bi)                                               \
  {                                                                       \
    size_t kr = (size_t)((kvb) + w*16 + srow)*128 + sgs*16;               \
    char* kd = (char*)khL[bi] + w*2048;                                   \
    gload16(KhB + kr,      kd);                                           \
    gload16(KhB + kr + 64, kd + 1024);                                    \
    size_t vr = (size_t)(w*16 + srow)*8192 + (size_t)(kvb)*2 + sgs*16;    \
    char* vd = (char*)vL[bi] + w*2048;                                    \
    gload16(VB + vr,      vd);                                            \
    gload16(VB + vr + 64, vd + 1024);                                     \
  }

  STAGE_KV(kv0, 0);
  __syncthreads();

  const int swz = (l15 >> 1) & 3;                 // row-swizzle for reads
  const int kfrag = l15*64 + (g ^ swz)*16;        // K b128 read offset

  for (int t = 0; t < 16; ++t){
    const int cb = t & 1;

    if (t < 15){
      STAGE_KV(kv0 + (t+1)*64, cb ^ 1);
    }

    // ---- S^T = K Q^T : S = kh*(qh+ql), K from LDS (exp2 domain) ----
    f32x4 s[4];
    #pragma unroll
    for (int ct=0; ct<4; ++ct){
      const char* kb = (const char*)khL[cb] + ct*2048;
      s16x8 kh0 = *(const s16x8*)(kb + kfrag);
      s16x8 kh1 = *(const s16x8*)(kb + 1024 + kfrag);
      f32x4 acc = {0.f,0.f,0.f,0.f};
      acc = __builtin_amdgcn_mfma_f32_16x16x32_bf16(kh0, ql0, acc, 0, 0, 0);
      acc = __builtin_amdgcn_mfma_f32_16x16x32_bf16(kh1, ql1, acc, 0, 0, 0);
      acc = __builtin_amdgcn_mfma_f32_16x16x32_bf16(kh0, qh0, acc, 0, 0, 0);
      acc = __builtin_amdgcn_mfma_f32_16x16x32_bf16(kh1, qh1, acc, 0, 0, 0);
      s[ct] = acc;   // s[ct][r] = S2[q=qrow+l15][k = kv + ct*16 + g*4 + r]
    }

    // ---- per-lane scalar online softmax (base 2, defer-max THR=8) ----
    float mx = s[0][0];
    #pragma unroll
    for (int ct=0;ct<4;++ct){
      #pragma unroll
      for (int r=0;r<4;++r) mx = fmaxf(mx, s[ct][r]);
    }
    mx = fmaxf(mx, __shfl_xor(mx, 16));
    mx = fmaxf(mx, __shfl_xor(mx, 32));
    if (!__all(mx <= m_run + 8.0f)){
      float mn = fmaxf(m_run, mx);
      float sc = fexp2(m_run - mn);
      m_run = mn;
      l_run *= sc;
      #pragma unroll
      for (int ot=0;ot<4;++ot) o_acc[ot] *= sc;
    }
    float rs = 0.f;
    s16x4 pbf[4];
    #pragma unroll
    for (int ct=0;ct<4;++ct){
      #pragma unroll
      for (int r=0;r<4;++r){
        float p = fexp2(s[ct][r] - m_run);
        rs += p;
        pbf[ct][r] = (short)f2bf(p);
      }
    }
    rs += __shfl_xor(rs, 16);
    rs += __shfl_xor(rs, 32);
    l_run += rs;

    // ---- O^T += V^T P^T : 16 x (16x16x16) MFMAs, V via swizzled LDS ----
    #pragma unroll
    for (int ot=0; ot<4; ++ot){
      const char* vbase = (const char*)vL[cb] + ot*2048 + l15*64;
      #pragma unroll
      for (int ct=0; ct<4; ++ct){
        int chunk = (((ct & 1) << 1) + (g >> 1)) ^ swz;
        s16x4 av = *(const s16x4*)(vbase + (ct>>1)*1024 + chunk*16 + (g&1)*8);
        o_acc[ot] = mfma16(av, pbf[ct], o_acc[ot]);
      }
    }

    __syncthreads();   // single barrier: drains stage(t+1), flips buffers
  }
  #undef STAGE_KV

  // ---- epilogue: O^T[o][q] in regs -> swizzled LDS transpose -> O[n][o] ----
  float* ep = (float*)((char*)vL + (size_t)w*4096);   // 4KB per wave
  #pragma unroll
  for (int ot=0;ot<4;++ot){
    int dw = l15*64 + ((ot*16 + g*4) ^ ((l15 & 7) << 2));
    *(f32x4*)(ep + dw) = o_acc[ot];      // rows q=l15, swizzled o
  }
  __syncthreads();
  {
    const int q4  = lane >> 2;
    const int seg = lane & 3;
    float* Ob = Opart + ((size_t)(ks*4 + b)*4096 + qrow)*64;
    #pragma unroll
    for (int c=0;c<4;++c){
      int o0 = seg*16 + c*4;
      f32x4 vv = *(const f32x4*)(ep + q4*64 + (o0 ^ ((q4 & 7) << 2)));
      *(f32x4*)(Ob + (size_t)q4*64 + o0) = vv;   // 1KB coalesced per inst
    }
  }
  if (lane < 16){
    Mst[(size_t)(ks*4 + b)*4096 + qrow + lane] = m_run;
    Lst[(size_t)(ks*4 + b)*4096 + qrow + lane] = l_run;
  }
}

// ---------------------------------------------------------------------------
// Kernel C: merge 4 KV-split partials (exp2 domain), then y = wc*O+bc ->
//  BN -> ReLU -> +img. Grid 512 = b(4) x ntile(64) x chalf(2).
// ---------------------------------------------------------------------------
__global__ __launch_bounds__(256) void final_proj(
    const float* __restrict__ Opart, const float* __restrict__ Mst,
    const float* __restrict__ Lst, const float* __restrict__ wc,
    const float* __restrict__ bc, const float* __restrict__ gm,
    const float* __restrict__ bt, const float* __restrict__ mu,
    const float* __restrict__ vr, const float* __restrict__ img,
    float* __restrict__ out)
{
  __shared__ float ol[64*64];
  __shared__ float scl[4][64];
  const int tid = threadIdx.x;
  const int idx = blockIdx.x;
  const int cs  = idx & 1;
  const int nt  = (idx >> 1) & 63;
  const int b   = idx >> 7;
  const int n0  = nt << 6;

  if (tid < 64){
    size_t rid = (size_t)b*4096 + n0 + tid;
    float m0 = Mst[0*16384 + rid], m1 = Mst[1*16384 + rid];
    float m2 = Mst[2*16384 + rid], m3 = Mst[3*16384 + rid];
    float mm = fmaxf(fmaxf(m0,m1), fmaxf(m2,m3));
    float s0 = fexp2(m0-mm), s1 = fexp2(m1-mm);
    float s2 = fexp2(m2-mm), s3 = fexp2(m3-mm);
    float li = s0*Lst[0*16384+rid] + s1*Lst[1*16384+rid]
             + s2*Lst[2*16384+rid] + s3*Lst[3*16384+rid];
    float inv = 1.0f / li;
    scl[0][tid] = s0*inv; scl[1][tid] = s1*inv;
    scl[2][tid] = s2*inv; scl[3][tid] = s3*inv;
  }
  __syncthreads();

  {
    const size_t base = ((size_t)b*4096 + n0)*64;
    for (int j=0;j<16;++j){
      int flat = tid + (j << 8);
      int n = flat >> 6, o = flat & 63;
      float v = Opart[0*(size_t)16384*64 + base + flat] * scl[0][n]
              + Opart[1*(size_t)16384*64 + base + flat] * scl[1][n]
              + Opart[2*(size_t)16384*64 + base + flat] * scl[2][n]
              + Opart[3*(size_t)16384*64 + base + flat] * scl[3][n];
      ol[(o << 6) + (n ^ (o & 31))] = v;
    }
  }
  __syncthreads();

  const int lane = tid & 63;
  const int w = __builtin_amdgcn_readfirstlane(tid >> 6);
  const int c0 = (cs << 6) + (w << 4);             // 16 channels per wave

  float acc[16];
  #pragma unroll
  for (int cc=0;cc<16;++cc) acc[cc] = 0.f;

  for (int o=0;o<64;++o){
    float v = ol[(o << 6) + (lane ^ (o & 31))];
    #pragma unroll
    for (int cc=0;cc<16;++cc)
      acc[cc] = fmaf(wc[(c0+cc)*64 + o], v, acc[cc]);
  }

  #pragma unroll
  for (int cc=0;cc<16;++cc){
    int c = c0 + cc;
    float inv = gm[c] * rsqrtf(vr[c] + 1e-5f);
    float sh  = bt[c] - mu[c]*inv;
    float y = (acc[cc] + bc[c]) * inv + sh;
    y = fmaxf(y, 0.f);
    size_t gi = ((size_t)(b*128 + c))*4096 + n0 + lane;
    out[gi] = img[gi] + y;
  }
}

// ---------------------------------------------------------------------------
extern "C" void kernel_launch(void* const* d_in, const int* in_sizes, int n_in,
                              void* d_out, int out_size, void* d_ws, size_t ws_size,
                              hipStream_t stream)
{
  const float* xr = (const float*)d_in[0];
  const float* xi = (const float*)d_in[1];
  const float* wq = (const float*)d_in[2];
  const float* bq = (const float*)d_in[3];
  const float* wk = (const float*)d_in[4];
  const float* bk = (const float*)d_in[5];
  const float* wv = (const float*)d_in[6];
  const float* bv = (const float*)d_in[7];
  const float* wc = (const float*)d_in[8];
  const float* bc = (const float*)d_in[9];
  const float* gm = (const float*)d_in[10];
  const float* bt = (const float*)d_in[11];
  const float* mu = (const float*)d_in[12];
  const float* vr = (const float*)d_in[13];
  float* out = (float*)d_out;

  // ws: Qh,Ql,Kh (2MB each) + Vt 2MB + Opart 16MB + M,L 0.5MB
  const size_t SZ = (size_t)4*4096*64;
  ushort* Qhw = (ushort*)d_ws;
  ushort* Qlw = Qhw + SZ;
  ushort* Khw = Qlw + SZ;
  ushort* Vtw = Khw + SZ;
  float*  Ow  = (float*)(Vtw + SZ);
  float*  Mw  = Ow + (size_t)16*4096*64;
  float*  Lw  = Mw + (size_t)16*4096;

  proj_qkv  <<<1024, 256, 0, stream>>>(xr, xi, wq, wk, wv, bq, bk, bv,
                                       Qhw, Qlw, Khw, Vtw);
  flash_attn<<<1024, 256, 0, stream>>>(Qhw, Qlw, Khw, Vtw, Ow, Mw, Lw);
  final_proj<<<512,  256, 0, stream>>>(Ow, Mw, Lw, wc, bc, gm, bt, mu, vr, xi, out);
}

// Round 21
// 77.124 us; speedup vs baseline: 1.1867x; 1.0511x over previous
//
#include <hip/hip_runtime.h>
#include <hip/hip_bf16.h>

typedef __attribute__((ext_vector_type(4))) float f32x4;
typedef __attribute__((ext_vector_type(8))) short s16x8;
typedef __attribute__((ext_vector_type(4))) short s16x4;

#define LOG2E 1.4426950408889634f

__device__ __forceinline__ ushort f2bf(float f){
  union { float f; unsigned u; } x; x.f = f;
  unsigned r = x.u + 0x7fffu + ((x.u >> 16) & 1u);
  return (ushort)(r >> 16);
}
__device__ __forceinline__ float bf2f(ushort h){
  union { unsigned u; float f; } x; x.u = ((unsigned)h) << 16;
  return x.f;
}

// fast 2^x: single v_exp_f32 (libm exp2f is NOT this without -ffast-math)
__device__ __forceinline__ float fexp2(float x){
#if __has_builtin(__builtin_amdgcn_exp2f)
  return __builtin_amdgcn_exp2f(x);
#else
  float r; asm("v_exp_f32 %0, %1" : "=v"(r) : "v"(x)); return r;
#endif
}

__device__ __forceinline__ void gload16(const void* g, void* l){
  __builtin_amdgcn_global_load_lds(
      (const __attribute__((address_space(1))) void*)g,
      (__attribute__((address_space(3))) void*)l, 16, 0, 0);
}

// K=16 bf16 MFMA (A,B = 4 bf16 in 2 VGPRs).
#if __has_builtin(__builtin_amdgcn_mfma_f32_16x16x16bf16_1k)
__device__ __forceinline__ f32x4 mfma16(s16x4 a, s16x4 b, f32x4 c){
  return __builtin_amdgcn_mfma_f32_16x16x16bf16_1k(a, b, c, 0, 0, 0);
}
#elif __has_builtin(__builtin_amdgcn_mfma_f32_16x16x16_bf16)
__device__ __forceinline__ f32x4 mfma16(s16x4 a, s16x4 b, f32x4 c){
  return __builtin_amdgcn_mfma_f32_16x16x16_bf16(a, b, c, 0, 0, 0);
}
#else
__device__ __forceinline__ f32x4 mfma16(s16x4 a, s16x4 b, f32x4 c){
  f32x4 d;
  asm volatile("v_mfma_f32_16x16x16_bf16 %0, %1, %2, %3\n\ts_nop 7\n\ts_nop 7"
               : "=v"(d) : "v"(a), "v"(b), "v"(c));
  return d;
}
#endif

// ---------------------------------------------------------------------------
// Kernel A: MFMA Q/K/V projections. Grid 1024 = b(4) x ntile(256); each
//  block owns a UNIQUE 16-px x-slice. BOTH x-tiles (xr,xi) staged up-front
//  into a 2x8KB double buffer with ONE barrier (overlapped loads).
//  Wave w = outputs [16w,16w+16). Q hi+lo (exp2-prescaled), K hi only,
//  V bf16 [o][n].
// ---------------------------------------------------------------------------
__global__ __launch_bounds__(256, 4) void proj_qkv(
    const float* __restrict__ xr, const float* __restrict__ xi,
    const float* __restrict__ wq, const float* __restrict__ wk,
    const float* __restrict__ wv,
    const float* __restrict__ bq, const float* __restrict__ bk,
    const float* __restrict__ bv,
    ushort* __restrict__ Qh, ushort* __restrict__ Ql,
    ushort* __restrict__ Kh, ushort* __restrict__ Vt)
{
  __shared__ __align__(16) float xL[2][128*16];   // 16 KB: [0]=xr, [1]=xi
  const int tid = threadIdx.x;
  const int idx = blockIdx.x;
  const int nt  = idx & 255;
  const int b   = idx >> 8;
  const int n0  = nt << 4;
  const int lane = tid & 63;
  const int w    = tid >> 6;
  const int l15  = lane & 15;
  const int g    = lane >> 4;
  const int obase = w << 4;                       // wave-uniform output base

  // stage [128c][16px] f32 into buffer bi
  #define STAGE_X16(src, bi)                                              \
  {                                                                       \
    const float* xs = (src) + (size_t)b*524288 + n0;                      \
    _Pragma("unroll")                                                     \
    for (int rdd = 0; rdd < 2; ++rdd){                                    \
      int chunk = rdd*256 + tid;             /* 0..511 */                 \
      int c = chunk >> 2, p4 = chunk & 3;                                 \
      gload16(xs + (size_t)c*4096 + p4*4, xL[bi] + rdd*1024 + w*256);     \
    }                                                                     \
  }
  #define BUILD_FRAGS16(bi, fh, fl)                                       \
  {                                                                       \
    _Pragma("unroll")                                                     \
    for (int kc = 0; kc < 4; ++kc){                                       \
      _Pragma("unroll")                                                   \
      for (int j = 0; j < 8; ++j){                                        \
        int c = kc*32 + g*8 + j;                                          \
        float a = xL[bi][c*16 + l15];                                     \
        ushort h = f2bf(a);                                               \
        fh[kc][j] = (short)h;                                             \
        fl[kc][j] = (short)f2bf(a - bf2f(h));                             \
      }                                                                   \
    }                                                                     \
  }
  #define LOAD_WFRAGS(wp, wh, wl4)                                        \
  {                                                                       \
    _Pragma("unroll")                                                     \
    for (int kc = 0; kc < 4; ++kc){                                       \
      const float* src = (wp) + (obase + l15)*128 + kc*32 + g*8;          \
      f32x4 a0 = *(const f32x4*)(src);                                    \
      f32x4 a1 = *(const f32x4*)(src + 4);                                \
      _Pragma("unroll")                                                   \
      for (int e = 0; e < 4; ++e){                                        \
        ushort h0 = f2bf(a0[e]);                                          \
        wh[kc][e]   = (short)h0;                                          \
        wl4[kc][e]  = (short)f2bf(a0[e] - bf2f(h0));                      \
        ushort h1 = f2bf(a1[e]);                                          \
        wh[kc][4+e]  = (short)h1;                                         \
        wl4[kc][4+e] = (short)f2bf(a1[e] - bf2f(h1));                     \
      }                                                                   \
    }                                                                     \
  }

  STAGE_X16(xr, 0);
  STAGE_X16(xi, 1);
  __syncthreads();                                // single drain for both

  // ---- phase 1: range_x -> Q (this wave's 16 outputs) ----
  {
    s16x8 xh[4], xl4[4];
    BUILD_FRAGS16(0, xh, xl4);
    s16x8 wfh[4], wfl[4];
    LOAD_WFRAGS(wq, wfh, wfl);
    f32x4 acc = {0.f,0.f,0.f,0.f};
    #pragma unroll
    for (int kc = 0; kc < 4; ++kc){
      acc = __builtin_amdgcn_mfma_f32_16x16x32_bf16(xh[kc],  wfh[kc], acc, 0,0,0);
      acc = __builtin_amdgcn_mfma_f32_16x16x32_bf16(xl4[kc], wfh[kc], acc, 0,0,0);
      acc = __builtin_amdgcn_mfma_f32_16x16x32_bf16(xh[kc],  wfl[kc], acc, 0,0,0);
    }
    float bqv = bq[obase + l15];
    #pragma unroll
    for (int r = 0; r < 4; ++r){
      float q = (acc[r] + bqv) * LOG2E;           // exp2-domain pre-scale
      ushort hi = f2bf(q);
      size_t a = (size_t)(b*4096 + n0 + g*4 + r)*64 + obase + l15;
      Qh[a] = hi; Ql[a] = f2bf(q - bf2f(hi));
    }
  }

  // ---- phase 2: img -> K, V ----
  {
    s16x8 xh[4], xl4[4];
    BUILD_FRAGS16(1, xh, xl4);
    // K (hi output only)
    {
      s16x8 wfh[4], wfl[4];
      LOAD_WFRAGS(wk, wfh, wfl);
      f32x4 acc = {0.f,0.f,0.f,0.f};
      #pragma unroll
      for (int kc = 0; kc < 4; ++kc){
        acc = __builtin_amdgcn_mfma_f32_16x16x32_bf16(xh[kc],  wfh[kc], acc, 0,0,0);
        acc = __builtin_amdgcn_mfma_f32_16x16x32_bf16(xl4[kc], wfh[kc], acc, 0,0,0);
        acc = __builtin_amdgcn_mfma_f32_16x16x32_bf16(xh[kc],  wfl[kc], acc, 0,0,0);
      }
      float bkv = bk[obase + l15];
      #pragma unroll
      for (int r = 0; r < 4; ++r){
        size_t a = (size_t)(b*4096 + n0 + g*4 + r)*64 + obase + l15;
        Kh[a] = f2bf(acc[r] + bkv);
      }
    }
    // V (swapped operands -> [o][n] layout)
    {
      s16x8 wfh[4], wfl[4];
      LOAD_WFRAGS(wv, wfh, wfl);
      f32x4 acc = {0.f,0.f,0.f,0.f};
      #pragma unroll
      for (int kc = 0; kc < 4; ++kc){
        acc = __builtin_amdgcn_mfma_f32_16x16x32_bf16(wfh[kc], xh[kc],  acc, 0,0,0);
        acc = __builtin_amdgcn_mfma_f32_16x16x32_bf16(wfl[kc], xh[kc],  acc, 0,0,0);
        acc = __builtin_amdgcn_mfma_f32_16x16x32_bf16(wfh[kc], xl4[kc], acc, 0,0,0);
      }
      #pragma unroll
      for (int r = 0; r < 4; ++r){
        int o = obase + g*4 + r;
        float v = acc[r] + bv[o];
        Vt[(size_t)(b*64 + o)*4096 + n0 + l15] = f2bf(v);
      }
    }
  }
  #undef STAGE_X16
  #undef BUILD_FRAGS16
  #undef LOAD_WFRAGS
}

// ---------------------------------------------------------------------------
// Kernel B: flash attention — frozen r17 compute structure; epilogue now
//  writes Opart as bf16 (halves partial-O traffic). Transposed orientation,
//  per-lane exp2 softmax, defer-max THR=8, K,V XOR-swizzled 16B,
//  double-buffered, ONE barrier/iter, XCD-aware remap. LDS 32KB. Grid 1024.
// ---------------------------------------------------------------------------
__global__ __launch_bounds__(256, 5) void flash_attn(
    const ushort* __restrict__ Qh, const ushort* __restrict__ Ql,
    const ushort* __restrict__ Kh, const ushort* __restrict__ Vt,
    ushort* __restrict__ Opart, float* __restrict__ Mst,
    float* __restrict__ Lst)
{
  __shared__ __align__(16) ushort khL[2][4096];   // 16KB
  __shared__ __align__(16) ushort vL[2][4096];    // 16KB (epilogue scratch too)

  const int tid  = threadIdx.x;
  const int idx  = blockIdx.x;
  const int xcd  = idx & 7;
  const int rest = idx >> 3;                 // 0..127
  const int b    = xcd >> 1;
  const int ks   = ((xcd & 1) << 1) | (rest >> 6);
  const int qt   = rest & 63;
  const int lane = tid & 63;
  const int w    = tid >> 6;
  const int l15  = lane & 15;
  const int g    = lane >> 4;
  const int qrow = qt*64 + w*16;
  const int kv0  = ks << 10;                 // 1024 kv per split
  const int srow = lane >> 2;
  const int sg   = lane & 3;
  const int sgs  = sg ^ ((srow >> 1) & 3);   // source chunk pre-swizzle (K & V)

  const size_t qoff = ((size_t)(b*4096 + qrow + l15))*64 + g*8;
  s16x8 qh0 = *(const s16x8*)(Qh + qoff);
  s16x8 qh1 = *(const s16x8*)(Qh + qoff + 32);
  s16x8 ql0 = *(const s16x8*)(Ql + qoff);
  s16x8 ql1 = *(const s16x8*)(Ql + qoff + 32);

  const char* KhB = (const char*)(Kh + (size_t)b*4096*64);
  const char* VB  = (const char*)(Vt + (size_t)b*64*4096);

  f32x4 o_acc[4];
  #pragma unroll
  for (int ot=0;ot<4;++ot) o_acc[ot] = (f32x4){0.f,0.f,0.f,0.f};
  float m_run = -1e30f, l_run = 0.f;

  #define STAGE_KV(kvb, bi)                                               \
  {                                                                       \
    size_t kr = (size_t)((kvb) + w*16 + srow)*128 + sgs*16;               \
    char* kd = (char*)khL[bi] + w*2048;                                   \
    gload16(KhB + kr,      kd);                                           \
    gload16(KhB + kr + 64, kd + 1024);                                    \
    size_t vr = (size_t)(w*16 + srow)*8192 + (size_t)(kvb)*2 + sgs*16;    \
    char* vd = (char*)vL[bi] + w*2048;                                    \
    gload16(VB + vr,      vd);                                            \
    gload16(VB + vr + 64, vd + 1024);                                     \
  }

  STAGE_KV(kv0, 0);
  __syncthreads();

  const int swz = (l15 >> 1) & 3;                 // row-swizzle for reads
  const int kfrag = l15*64 + (g ^ swz)*16;        // K b128 read offset

  for (int t = 0; t < 16; ++t){
    const int cb = t & 1;

    if (t < 15){
      STAGE_KV(kv0 + (t+1)*64, cb ^ 1);
    }

    // ---- S^T = K Q^T : S = kh*(qh+ql), K from LDS (exp2 domain) ----
    f32x4 s[4];
    #pragma unroll
    for (int ct=0; ct<4; ++ct){
      const char* kb = (const char*)khL[cb] + ct*2048;
      s16x8 kh0 = *(const s16x8*)(kb + kfrag);
      s16x8 kh1 = *(const s16x8*)(kb + 1024 + kfrag);
      f32x4 acc = {0.f,0.f,0.f,0.f};
      acc = __builtin_amdgcn_mfma_f32_16x16x32_bf16(kh0, ql0, acc, 0, 0, 0);
      acc = __builtin_amdgcn_mfma_f32_16x16x32_bf16(kh1, ql1, acc, 0, 0, 0);
      acc = __builtin_amdgcn_mfma_f32_16x16x32_bf16(kh0, qh0, acc, 0, 0, 0);
      acc = __builtin_amdgcn_mfma_f32_16x16x32_bf16(kh1, qh1, acc, 0, 0, 0);
      s[ct] = acc;   // s[ct][r] = S2[q=qrow+l15][k = kv + ct*16 + g*4 + r]
    }

    // ---- per-lane scalar online softmax (base 2, defer-max THR=8) ----
    float mx = s[0][0];
    #pragma unroll
    for (int ct=0;ct<4;++ct){
      #pragma unroll
      for (int r=0;r<4;++r) mx = fmaxf(mx, s[ct][r]);
    }
    mx = fmaxf(mx, __shfl_xor(mx, 16));
    mx = fmaxf(mx, __shfl_xor(mx, 32));
    if (!__all(mx <= m_run + 8.0f)){
      float mn = fmaxf(m_run, mx);
      float sc = fexp2(m_run - mn);
      m_run = mn;
      l_run *= sc;
      #pragma unroll
      for (int ot=0;ot<4;++ot) o_acc[ot] *= sc;
    }
    float rs = 0.f;
    s16x4 pbf[4];
    #pragma unroll
    for (int ct=0;ct<4;++ct){
      #pragma unroll
      for (int r=0;r<4;++r){
        float p = fexp2(s[ct][r] - m_run);
        rs += p;
        pbf[ct][r] = (short)f2bf(p);
      }
    }
    rs += __shfl_xor(rs, 16);
    rs += __shfl_xor(rs, 32);
    l_run += rs;

    // ---- O^T += V^T P^T : 16 x (16x16x16) MFMAs, V via swizzled LDS ----
    #pragma unroll
    for (int ot=0; ot<4; ++ot){
      const char* vbase = (const char*)vL[cb] + ot*2048 + l15*64;
      #pragma unroll
      for (int ct=0; ct<4; ++ct){
        int chunk = (((ct & 1) << 1) + (g >> 1)) ^ swz;
        s16x4 av = *(const s16x4*)(vbase + (ct>>1)*1024 + chunk*16 + (g&1)*8);
        o_acc[ot] = mfma16(av, pbf[ct], o_acc[ot]);
      }
    }

    __syncthreads();   // single barrier: drains stage(t+1), flips buffers
  }
  #undef STAGE_KV

  // ---- epilogue: O^T[o][q] -> swizzled LDS transpose -> bf16 O[n][o] ----
  float* ep = (float*)((char*)vL + (size_t)w*4096);   // 4KB per wave
  #pragma unroll
  for (int ot=0;ot<4;++ot){
    int dw = l15*64 + ((ot*16 + g*4) ^ ((l15 & 7) << 2));
    *(f32x4*)(ep + dw) = o_acc[ot];      // rows q=l15, swizzled o
  }
  __syncthreads();
  {
    const int q4  = lane >> 2;
    const int seg = lane & 3;
    ushort* Ob = Opart + ((size_t)(ks*4 + b)*4096 + qrow)*64;
    #pragma unroll
    for (int c=0;c<4;++c){
      int o0 = seg*16 + c*4;
      f32x4 vv = *(const f32x4*)(ep + q4*64 + (o0 ^ ((q4 & 7) << 2)));
      ushort4 pk;
      pk.x = f2bf(vv[0]); pk.y = f2bf(vv[1]);
      pk.z = f2bf(vv[2]); pk.w = f2bf(vv[3]);
      *(ushort4*)(Ob + (size_t)q4*64 + o0) = pk;   // 512B coalesced per inst
    }
  }
  if (lane < 16){
    Mst[(size_t)(ks*4 + b)*4096 + qrow + lane] = m_run;
    Lst[(size_t)(ks*4 + b)*4096 + qrow + lane] = l_run;
  }
}

// ---------------------------------------------------------------------------
// Kernel C: merge 4 bf16 KV-split partials (exp2 domain), then y = wc*O+bc
//  -> BN -> ReLU -> +img. Grid 512 = b(4) x ntile(64) x chalf(2).
// ---------------------------------------------------------------------------
__global__ __launch_bounds__(256) void final_proj(
    const ushort* __restrict__ Opart, const float* __restrict__ Mst,
    const float* __restrict__ Lst, const float* __restrict__ wc,
    const float* __restrict__ bc, const float* __restrict__ gm,
    const float* __restrict__ bt, const float* __restrict__ mu,
    const float* __restrict__ vr, const float* __restrict__ img,
    float* __restrict__ out)
{
  __shared__ float ol[64*64];
  __shared__ float scl[4][64];
  const int tid = threadIdx.x;
  const int idx = blockIdx.x;
  const int cs  = idx & 1;
  const int nt  = (idx >> 1) & 63;
  const int b   = idx >> 7;
  const int n0  = nt << 6;

  if (tid < 64){
    size_t rid = (size_t)b*4096 + n0 + tid;
    float m0 = Mst[0*16384 + rid], m1 = Mst[1*16384 + rid];
    float m2 = Mst[2*16384 + rid], m3 = Mst[3*16384 + rid];
    float mm = fmaxf(fmaxf(m0,m1), fmaxf(m2,m3));
    float s0 = fexp2(m0-mm), s1 = fexp2(m1-mm);
    float s2 = fexp2(m2-mm), s3 = fexp2(m3-mm);
    float li = s0*Lst[0*16384+rid] + s1*Lst[1*16384+rid]
             + s2*Lst[2*16384+rid] + s3*Lst[3*16384+rid];
    float inv = 1.0f / li;
    scl[0][tid] = s0*inv; scl[1][tid] = s1*inv;
    scl[2][tid] = s2*inv; scl[3][tid] = s3*inv;
  }
  __syncthreads();

  {
    const size_t base = ((size_t)b*4096 + n0)*64;
    for (int j=0;j<16;++j){
      int flat = tid + (j << 8);
      int n = flat >> 6, o = flat & 63;
      float v = bf2f(Opart[0*(size_t)16384*64 + base + flat]) * scl[0][n]
              + bf2f(Opart[1*(size_t)16384*64 + base + flat]) * scl[1][n]
              + bf2f(Opart[2*(size_t)16384*64 + base + flat]) * scl[2][n]
              + bf2f(Opart[3*(size_t)16384*64 + base + flat]) * scl[3][n];
      ol[(o << 6) + (n ^ (o & 31))] = v;
    }
  }
  __syncthreads();

  const int lane = tid & 63;
  const int w = __builtin_amdgcn_readfirstlane(tid >> 6);
  const int c0 = (cs << 6) + (w << 4);             // 16 channels per wave

  float acc[16];
  #pragma unroll
  for (int cc=0;cc<16;++cc) acc[cc] = 0.f;

  for (int o=0;o<64;++o){
    float v = ol[(o << 6) + (lane ^ (o & 31))];
    #pragma unroll
    for (int cc=0;cc<16;++cc)
      acc[cc] = fmaf(wc[(c0+cc)*64 + o], v, acc[cc]);
  }

  #pragma unroll
  for (int cc=0;cc<16;++cc){
    int c = c0 + cc;
    float inv = gm[c] * rsqrtf(vr[c] + 1e-5f);
    float sh  = bt[c] - mu[c]*inv;
    float y = (acc[cc] + bc[c]) * inv + sh;
    y = fmaxf(y, 0.f);
    size_t gi = ((size_t)(b*128 + c))*4096 + n0 + lane;
    out[gi] = img[gi] + y;
  }
}

// ---------------------------------------------------------------------------
extern "C" void kernel_launch(void* const* d_in, const int* in_sizes, int n_in,
                              void* d_out, int out_size, void* d_ws, size_t ws_size,
                              hipStream_t stream)
{
  const float* xr = (const float*)d_in[0];
  const float* xi = (const float*)d_in[1];
  const float* wq = (const float*)d_in[2];
  const float* bq = (const float*)d_in[3];
  const float* wk = (const float*)d_in[4];
  const float* bk = (const float*)d_in[5];
  const float* wv = (const float*)d_in[6];
  const float* bv = (const float*)d_in[7];
  const float* wc = (const float*)d_in[8];
  const float* bc = (const float*)d_in[9];
  const float* gm = (const float*)d_in[10];
  const float* bt = (const float*)d_in[11];
  const float* mu = (const float*)d_in[12];
  const float* vr = (const float*)d_in[13];
  float* out = (float*)d_out;

  // ws: Qh,Ql,Kh,Vt (2MB each) + Opart bf16 8MB + M,L 0.5MB
  const size_t SZ = (size_t)4*4096*64;
  ushort* Qhw = (ushort*)d_ws;
  ushort* Qlw = Qhw + SZ;
  ushort* Khw = Qlw + SZ;
  ushort* Vtw = Khw + SZ;
  ushort* Ow  = Vtw + SZ;
  float*  Mw  = (float*)(Ow + (size_t)16*4096*64);
  float*  Lw  = Mw + (size_t)16*4096;

  proj_qkv  <<<1024, 256, 0, stream>>>(xr, xi, wq, wk, wv, bq, bk, bv,
                                       Qhw, Qlw, Khw, Vtw);
  flash_attn<<<1024, 256, 0, stream>>>(Qhw, Qlw, Khw, Vtw, Ow, Mw, Lw);
  final_proj<<<512,  256, 0, stream>>>(Ow, Mw, Lw, wc, bc, gm, bt, mu, vr, xi, out);
}

// Round 22
// 76.052 us; speedup vs baseline: 1.2034x; 1.0141x over previous
//
#include <hip/hip_runtime.h>
#include <hip/hip_bf16.h>

typedef __attribute__((ext_vector_type(4))) float f32x4;
typedef __attribute__((ext_vector_type(8))) short s16x8;
typedef __attribute__((ext_vector_type(4))) short s16x4;

#define LOG2E 1.4426950408889634f

__device__ __forceinline__ ushort f2bf(float f){
  union { float f; unsigned u; } x; x.f = f;
  unsigned r = x.u + 0x7fffu + ((x.u >> 16) & 1u);
  return (ushort)(r >> 16);
}
__device__ __forceinline__ float bf2f(ushort h){
  union { unsigned u; float f; } x; x.u = ((unsigned)h) << 16;
  return x.f;
}

// fast 2^x: single v_exp_f32 (libm exp2f is NOT this without -ffast-math)
__device__ __forceinline__ float fexp2(float x){
#if __has_builtin(__builtin_amdgcn_exp2f)
  return __builtin_amdgcn_exp2f(x);
#else
  float r; asm("v_exp_f32 %0, %1" : "=v"(r) : "v"(x)); return r;
#endif
}

__device__ __forceinline__ void gload16(const void* g, void* l){
  __builtin_amdgcn_global_load_lds(
      (const __attribute__((address_space(1))) void*)g,
      (__attribute__((address_space(3))) void*)l, 16, 0, 0);
}

// K=16 bf16 MFMA (A,B = 4 bf16 in 2 VGPRs).
#if __has_builtin(__builtin_amdgcn_mfma_f32_16x16x16bf16_1k)
__device__ __forceinline__ f32x4 mfma16(s16x4 a, s16x4 b, f32x4 c){
  return __builtin_amdgcn_mfma_f32_16x16x16bf16_1k(a, b, c, 0, 0, 0);
}
#elif __has_builtin(__builtin_amdgcn_mfma_f32_16x16x16_bf16)
__device__ __forceinline__ f32x4 mfma16(s16x4 a, s16x4 b, f32x4 c){
  return __builtin_amdgcn_mfma_f32_16x16x16_bf16(a, b, c, 0, 0, 0);
}
#else
__device__ __forceinline__ f32x4 mfma16(s16x4 a, s16x4 b, f32x4 c){
  f32x4 d;
  asm volatile("v_mfma_f32_16x16x16_bf16 %0, %1, %2, %3\n\ts_nop 7\n\ts_nop 7"
               : "=v"(d) : "v"(a), "v"(b), "v"(c));
  return d;
}
#endif

// ---------------------------------------------------------------------------
// Kernel A: MFMA Q/K/V projections. Grid 1024 = b(4) x ntile(256); each
//  block owns a UNIQUE 16-px x-slice. BOTH x-tiles (xr,xi) staged up-front
//  into a 2x8KB double buffer with ONE barrier (overlapped loads).
//  Wave w = outputs [16w,16w+16). Q hi+lo (exp2-prescaled), K hi only,
//  V bf16 [o][n].
// ---------------------------------------------------------------------------
__global__ __launch_bounds__(256, 4) void proj_qkv(
    const float* __restrict__ xr, const float* __restrict__ xi,
    const float* __restrict__ wq, const float* __restrict__ wk,
    const float* __restrict__ wv,
    const float* __restrict__ bq, const float* __restrict__ bk,
    const float* __restrict__ bv,
    ushort* __restrict__ Qh, ushort* __restrict__ Ql,
    ushort* __restrict__ Kh, ushort* __restrict__ Vt)
{
  __shared__ __align__(16) float xL[2][128*16];   // 16 KB: [0]=xr, [1]=xi
  const int tid = threadIdx.x;
  const int idx = blockIdx.x;
  const int nt  = idx & 255;
  const int b   = idx >> 8;
  const int n0  = nt << 4;
  const int lane = tid & 63;
  const int w    = tid >> 6;
  const int l15  = lane & 15;
  const int g    = lane >> 4;
  const int obase = w << 4;                       // wave-uniform output base

  // stage [128c][16px] f32 into buffer bi
  #define STAGE_X16(src, bi)                                              \
  {                                                                       \
    const float* xs = (src) + (size_t)b*524288 + n0;                      \
    _Pragma("unroll")                                                     \
    for (int rdd = 0; rdd < 2; ++rdd){                                    \
      int chunk = rdd*256 + tid;             /* 0..511 */                 \
      int c = chunk >> 2, p4 = chunk & 3;                                 \
      gload16(xs + (size_t)c*4096 + p4*4, xL[bi] + rdd*1024 + w*256);     \
    }                                                                     \
  }
  #define BUILD_FRAGS16(bi, fh, fl)                                       \
  {                                                                       \
    _Pragma("unroll")                                                     \
    for (int kc = 0; kc < 4; ++kc){                                       \
      _Pragma("unroll")                                                   \
      for (int j = 0; j < 8; ++j){                                        \
        int c = kc*32 + g*8 + j;                                          \
        float a = xL[bi][c*16 + l15];                                     \
        ushort h = f2bf(a);                                               \
        fh[kc][j] = (short)h;                                             \
        fl[kc][j] = (short)f2bf(a - bf2f(h));                             \
      }                                                                   \
    }                                                                     \
  }
  #define LOAD_WFRAGS(wp, wh, wl4)                                        \
  {                                                                       \
    _Pragma("unroll")                                                     \
    for (int kc = 0; kc < 4; ++kc){                                       \
      const float* src = (wp) + (obase + l15)*128 + kc*32 + g*8;          \
      f32x4 a0 = *(const f32x4*)(src);                                    \
      f32x4 a1 = *(const f32x4*)(src + 4);                                \
      _Pragma("unroll")                                                   \
      for (int e = 0; e < 4; ++e){                                        \
        ushort h0 = f2bf(a0[e]);                                          \
        wh[kc][e]   = (short)h0;                                          \
        wl4[kc][e]  = (short)f2bf(a0[e] - bf2f(h0));                      \
        ushort h1 = f2bf(a1[e]);                                          \
        wh[kc][4+e]  = (short)h1;                                         \
        wl4[kc][4+e] = (short)f2bf(a1[e] - bf2f(h1));                     \
      }                                                                   \
    }                                                                     \
  }

  STAGE_X16(xr, 0);
  STAGE_X16(xi, 1);
  __syncthreads();                                // single drain for both

  // ---- phase 1: range_x -> Q (this wave's 16 outputs) ----
  {
    s16x8 xh[4], xl4[4];
    BUILD_FRAGS16(0, xh, xl4);
    s16x8 wfh[4], wfl[4];
    LOAD_WFRAGS(wq, wfh, wfl);
    f32x4 acc = {0.f,0.f,0.f,0.f};
    #pragma unroll
    for (int kc = 0; kc < 4; ++kc){
      acc = __builtin_amdgcn_mfma_f32_16x16x32_bf16(xh[kc],  wfh[kc], acc, 0,0,0);
      acc = __builtin_amdgcn_mfma_f32_16x16x32_bf16(xl4[kc], wfh[kc], acc, 0,0,0);
      acc = __builtin_amdgcn_mfma_f32_16x16x32_bf16(xh[kc],  wfl[kc], acc, 0,0,0);
    }
    float bqv = bq[obase + l15];
    #pragma unroll
    for (int r = 0; r < 4; ++r){
      float q = (acc[r] + bqv) * LOG2E;           // exp2-domain pre-scale
      ushort hi = f2bf(q);
      size_t a = (size_t)(b*4096 + n0 + g*4 + r)*64 + obase + l15;
      Qh[a] = hi; Ql[a] = f2bf(q - bf2f(hi));
    }
  }

  // ---- phase 2: img -> K, V ----
  {
    s16x8 xh[4], xl4[4];
    BUILD_FRAGS16(1, xh, xl4);
    // K (hi output only)
    {
      s16x8 wfh[4], wfl[4];
      LOAD_WFRAGS(wk, wfh, wfl);
      f32x4 acc = {0.f,0.f,0.f,0.f};
      #pragma unroll
      for (int kc = 0; kc < 4; ++kc){
        acc = __builtin_amdgcn_mfma_f32_16x16x32_bf16(xh[kc],  wfh[kc], acc, 0,0,0);
        acc = __builtin_amdgcn_mfma_f32_16x16x32_bf16(xl4[kc], wfh[kc], acc, 0,0,0);
        acc = __builtin_amdgcn_mfma_f32_16x16x32_bf16(xh[kc],  wfl[kc], acc, 0,0,0);
      }
      float bkv = bk[obase + l15];
      #pragma unroll
      for (int r = 0; r < 4; ++r){
        size_t a = (size_t)(b*4096 + n0 + g*4 + r)*64 + obase + l15;
        Kh[a] = f2bf(acc[r] + bkv);
      }
    }
    // V (swapped operands -> [o][n] layout)
    {
      s16x8 wfh[4], wfl[4];
      LOAD_WFRAGS(wv, wfh, wfl);
      f32x4 acc = {0.f,0.f,0.f,0.f};
      #pragma unroll
      for (int kc = 0; kc < 4; ++kc){
        acc = __builtin_amdgcn_mfma_f32_16x16x32_bf16(wfh[kc], xh[kc],  acc, 0,0,0);
        acc = __builtin_amdgcn_mfma_f32_16x16x32_bf16(wfl[kc], xh[kc],  acc, 0,0,0);
        acc = __builtin_amdgcn_mfma_f32_16x16x32_bf16(wfh[kc], xl4[kc], acc, 0,0,0);
      }
      #pragma unroll
      for (int r = 0; r < 4; ++r){
        int o = obase + g*4 + r;
        float v = acc[r] + bv[o];
        Vt[(size_t)(b*64 + o)*4096 + n0 + l15] = f2bf(v);
      }
    }
  }
  #undef STAGE_X16
  #undef BUILD_FRAGS16
  #undef LOAD_WFRAGS
}

// ---------------------------------------------------------------------------
// Kernel B: flash attention — frozen r17 compute structure; epilogue now
//  writes Opart as bf16 (halves partial-O traffic). Transposed orientation,
//  per-lane exp2 softmax, defer-max THR=8, K,V XOR-swizzled 16B,
//  double-buffered, ONE barrier/iter, XCD-aware remap. LDS 32KB. Grid 1024.
// ---------------------------------------------------------------------------
__global__ __launch_bounds__(256, 5) void flash_attn(
    const ushort* __restrict__ Qh, const ushort* __restrict__ Ql,
    const ushort* __restrict__ Kh, const ushort* __restrict__ Vt,
    ushort* __restrict__ Opart, float* __restrict__ Mst,
    float* __restrict__ Lst)
{
  __shared__ __align__(16) ushort khL[2][4096];   // 16KB
  __shared__ __align__(16) ushort vL[2][4096];    // 16KB (epilogue scratch too)

  const int tid  = threadIdx.x;
  const int idx  = blockIdx.x;
  const int xcd  = idx & 7;
  const int rest = idx >> 3;                 // 0..127
  const int b    = xcd >> 1;
  const int ks   = ((xcd & 1) << 1) | (rest >> 6);
  const int qt   = rest & 63;
  const int lane = tid & 63;
  const int w    = tid >> 6;
  const int l15  = lane & 15;
  const int g    = lane >> 4;
  const int qrow = qt*64 + w*16;
  const int kv0  = ks << 10;                 // 1024 kv per split
  const int srow = lane >> 2;
  const int sg   = lane & 3;
  const int sgs  = sg ^ ((srow >> 1) & 3);   // source chunk pre-swizzle (K & V)

  const size_t qoff = ((size_t)(b*4096 + qrow + l15))*64 + g*8;
  s16x8 qh0 = *(const s16x8*)(Qh + qoff);
  s16x8 qh1 = *(const s16x8*)(Qh + qoff + 32);
  s16x8 ql0 = *(const s16x8*)(Ql + qoff);
  s16x8 ql1 = *(const s16x8*)(Ql + qoff + 32);

  const char* KhB = (const char*)(Kh + (size_t)b*4096*64);
  const char* VB  = (const char*)(Vt + (size_t)b*64*4096);

  f32x4 o_acc[4];
  #pragma unroll
  for (int ot=0;ot<4;++ot) o_acc[ot] = (f32x4){0.f,0.f,0.f,0.f};
  float m_run = -1e30f, l_run = 0.f;

  #define STAGE_KV(kvb, bi)                                               \
  {                                                                       \
    size_t kr = (size_t)((kvb) + w*16 + srow)*128 + sgs*16;               \
    char* kd = (char*)khL[bi] + w*2048;                                   \
    gload16(KhB + kr,      kd);                                           \
    gload16(KhB + kr + 64, kd + 1024);                                    \
    size_t vr = (size_t)(w*16 + srow)*8192 + (size_t)(kvb)*2 + sgs*16;    \
    char* vd = (char*)vL[bi] + w*2048;                                    \
    gload16(VB + vr,      vd);                                            \
    gload16(VB + vr + 64, vd + 1024);                                     \
  }

  STAGE_KV(kv0, 0);
  __syncthreads();

  const int swz = (l15 >> 1) & 3;                 // row-swizzle for reads
  const int kfrag = l15*64 + (g ^ swz)*16;        // K b128 read offset

  for (int t = 0; t < 16; ++t){
    const int cb = t & 1;

    if (t < 15){
      STAGE_KV(kv0 + (t+1)*64, cb ^ 1);
    }

    // ---- S^T = K Q^T : S = kh*(qh+ql), K from LDS (exp2 domain) ----
    f32x4 s[4];
    #pragma unroll
    for (int ct=0; ct<4; ++ct){
      const char* kb = (const char*)khL[cb] + ct*2048;
      s16x8 kh0 = *(const s16x8*)(kb + kfrag);
      s16x8 kh1 = *(const s16x8*)(kb + 1024 + kfrag);
      f32x4 acc = {0.f,0.f,0.f,0.f};
      acc = __builtin_amdgcn_mfma_f32_16x16x32_bf16(kh0, ql0, acc, 0, 0, 0);
      acc = __builtin_amdgcn_mfma_f32_16x16x32_bf16(kh1, ql1, acc, 0, 0, 0);
      acc = __builtin_amdgcn_mfma_f32_16x16x32_bf16(kh0, qh0, acc, 0, 0, 0);
      acc = __builtin_amdgcn_mfma_f32_16x16x32_bf16(kh1, qh1, acc, 0, 0, 0);
      s[ct] = acc;   // s[ct][r] = S2[q=qrow+l15][k = kv + ct*16 + g*4 + r]
    }

    // ---- per-lane scalar online softmax (base 2, defer-max THR=8) ----
    float mx = s[0][0];
    #pragma unroll
    for (int ct=0;ct<4;++ct){
      #pragma unroll
      for (int r=0;r<4;++r) mx = fmaxf(mx, s[ct][r]);
    }
    mx = fmaxf(mx, __shfl_xor(mx, 16));
    mx = fmaxf(mx, __shfl_xor(mx, 32));
    if (!__all(mx <= m_run + 8.0f)){
      float mn = fmaxf(m_run, mx);
      float sc = fexp2(m_run - mn);
      m_run = mn;
      l_run *= sc;
      #pragma unroll
      for (int ot=0;ot<4;++ot) o_acc[ot] *= sc;
    }
    float rs = 0.f;
    s16x4 pbf[4];
    #pragma unroll
    for (int ct=0;ct<4;++ct){
      #pragma unroll
      for (int r=0;r<4;++r){
        float p = fexp2(s[ct][r] - m_run);
        rs += p;
        pbf[ct][r] = (short)f2bf(p);
      }
    }
    rs += __shfl_xor(rs, 16);
    rs += __shfl_xor(rs, 32);
    l_run += rs;

    // ---- O^T += V^T P^T : 16 x (16x16x16) MFMAs, V via swizzled LDS ----
    #pragma unroll
    for (int ot=0; ot<4; ++ot){
      const char* vbase = (const char*)vL[cb] + ot*2048 + l15*64;
      #pragma unroll
      for (int ct=0; ct<4; ++ct){
        int chunk = (((ct & 1) << 1) + (g >> 1)) ^ swz;
        s16x4 av = *(const s16x4*)(vbase + (ct>>1)*1024 + chunk*16 + (g&1)*8);
        o_acc[ot] = mfma16(av, pbf[ct], o_acc[ot]);
      }
    }

    __syncthreads();   // single barrier: drains stage(t+1), flips buffers
  }
  #undef STAGE_KV

  // ---- epilogue: O^T[o][q] -> swizzled LDS transpose -> bf16 O[n][o] ----
  float* ep = (float*)((char*)vL + (size_t)w*4096);   // 4KB per wave
  #pragma unroll
  for (int ot=0;ot<4;++ot){
    int dw = l15*64 + ((ot*16 + g*4) ^ ((l15 & 7) << 2));
    *(f32x4*)(ep + dw) = o_acc[ot];      // rows q=l15, swizzled o
  }
  __syncthreads();
  {
    const int q4  = lane >> 2;
    const int seg = lane & 3;
    ushort* Ob = Opart + ((size_t)(ks*4 + b)*4096 + qrow)*64;
    #pragma unroll
    for (int c=0;c<4;++c){
      int o0 = seg*16 + c*4;
      f32x4 vv = *(const f32x4*)(ep + q4*64 + (o0 ^ ((q4 & 7) << 2)));
      ushort4 pk;
      pk.x = f2bf(vv[0]); pk.y = f2bf(vv[1]);
      pk.z = f2bf(vv[2]); pk.w = f2bf(vv[3]);
      *(ushort4*)(Ob + (size_t)q4*64 + o0) = pk;   // 512B coalesced per inst
    }
  }
  if (lane < 16){
    Mst[(size_t)(ks*4 + b)*4096 + qrow + lane] = m_run;
    Lst[(size_t)(ks*4 + b)*4096 + qrow + lane] = l_run;
  }
}

// ---------------------------------------------------------------------------
// Kernel C: merge 4 bf16 KV-split partials (exp2 domain), then y = wc*O+bc
//  -> BN -> ReLU -> +img. Grid 512 = b(4) x ntile(64) x chalf(2).
// ---------------------------------------------------------------------------
__global__ __launch_bounds__(256) void final_proj(
    const ushort* __restrict__ Opart, const float* __restrict__ Mst,
    const float* __restrict__ Lst, const float* __restrict__ wc,
    const float* __restrict__ bc, const float* __restrict__ gm,
    const float* __restrict__ bt, const float* __restrict__ mu,
    const float* __restrict__ vr, const float* __restrict__ img,
    float* __restrict__ out)
{
  __shared__ float ol[64*64];
  __shared__ float scl[4][64];
  const int tid = threadIdx.x;
  const int idx = blockIdx.x;
  const int cs  = idx & 1;
  const int nt  = (idx >> 1) & 63;
  const int b   = idx >> 7;
  const int n0  = nt << 6;

  if (tid < 64){
    size_t rid = (size_t)b*4096 + n0 + tid;
    float m0 = Mst[0*16384 + rid], m1 = Mst[1*16384 + rid];
    float m2 = Mst[2*16384 + rid], m3 = Mst[3*16384 + rid];
    float mm = fmaxf(fmaxf(m0,m1), fmaxf(m2,m3));
    float s0 = fexp2(m0-mm), s1 = fexp2(m1-mm);
    float s2 = fexp2(m2-mm), s3 = fexp2(m3-mm);
    float li = s0*Lst[0*16384+rid] + s1*Lst[1*16384+rid]
             + s2*Lst[2*16384+rid] + s3*Lst[3*16384+rid];
    float inv = 1.0f / li;
    scl[0][tid] = s0*inv; scl[1][tid] = s1*inv;
    scl[2][tid] = s2*inv; scl[3][tid] = s3*inv;
  }
  __syncthreads();

  {
    const size_t base = ((size_t)b*4096 + n0)*64;
    for (int j=0;j<16;++j){
      int flat = tid + (j << 8);
      int n = flat >> 6, o = flat & 63;
      float v = bf2f(Opart[0*(size_t)16384*64 + base + flat]) * scl[0][n]
              + bf2f(Opart[1*(size_t)16384*64 + base + flat]) * scl[1][n]
              + bf2f(Opart[2*(size_t)16384*64 + base + flat]) * scl[2][n]
              + bf2f(Opart[3*(size_t)16384*64 + base + flat]) * scl[3][n];
      ol[(o << 6) + (n ^ (o & 31))] = v;
    }
  }
  __syncthreads();

  const int lane = tid & 63;
  const int w = __builtin_amdgcn_readfirstlane(tid >> 6);
  const int c0 = (cs << 6) + (w << 4);             // 16 channels per wave

  float acc[16];
  #pragma unroll
  for (int cc=0;cc<16;++cc) acc[cc] = 0.f;

  for (int o=0;o<64;++o){
    float v = ol[(o << 6) + (lane ^ (o & 31))];
    #pragma unroll
    for (int cc=0;cc<16;++cc)
      acc[cc] = fmaf(wc[(c0+cc)*64 + o], v, acc[cc]);
  }

  #pragma unroll
  for (int cc=0;cc<16;++cc){
    int c = c0 + cc;
    float inv = gm[c] * rsqrtf(vr[c] + 1e-5f);
    float sh  = bt[c] - mu[c]*inv;
    float y = (acc[cc] + bc[c]) * inv + sh;
    y = fmaxf(y, 0.f);
    size_t gi = ((size_t)(b*128 + c))*4096 + n0 + lane;
    out[gi] = img[gi] + y;
  }
}

// ---------------------------------------------------------------------------
extern "C" void kernel_launch(void* const* d_in, const int* in_sizes, int n_in,
                              void* d_out, int out_size, void* d_ws, size_t ws_size,
                              hipStream_t stream)
{
  const float* xr = (const float*)d_in[0];
  const float* xi = (const float*)d_in[1];
  const float* wq = (const float*)d_in[2];
  const float* bq = (const float*)d_in[3];
  const float* wk = (const float*)d_in[4];
  const float* bk = (const float*)d_in[5];
  const float* wv = (const float*)d_in[6];
  const float* bv = (const float*)d_in[7];
  const float* wc = (const float*)d_in[8];
  const float* bc = (const float*)d_in[9];
  const float* gm = (const float*)d_in[10];
  const float* bt = (const float*)d_in[11];
  const float* mu = (const float*)d_in[12];
  const float* vr = (const float*)d_in[13];
  float* out = (float*)d_out;

  // ws: Qh,Ql,Kh,Vt (2MB each) + Opart bf16 8MB + M,L 0.5MB
  const size_t SZ = (size_t)4*4096*64;
  ushort* Qhw = (ushort*)d_ws;
  ushort* Qlw = Qhw + SZ;
  ushort* Khw = Qlw + SZ;
  ushort* Vtw = Khw + SZ;
  ushort* Ow  = Vtw + SZ;
  float*  Mw  = (float*)(Ow + (size_t)16*4096*64);
  float*  Lw  = Mw + (size_t)16*4096;

  proj_qkv  <<<1024, 256, 0, stream>>>(xr, xi, wq, wk, wv, bq, bk, bv,
                                       Qhw, Qlw, Khw, Vtw);
  flash_attn<<<1024, 256, 0, stream>>>(Qhw, Qlw, Khw, Vtw, Ow, Mw, Lw);
  final_proj<<<512,  256, 0, stream>>>(Ow, Mw, Lw, wc, bc, gm, bt, mu, vr, xi, out);
}